// Round 2
// baseline (860.610 us; speedup 1.0000x reference)
//
#include <hip/hip_runtime.h>

#define B_DIM 4
#define T_DIM 300
#define U_DIM 80
#define UP1   81
#define V_DIM 1024
#define NINNER 512
#define NROWS (B_DIM * T_DIM * UP1)   /* 97200 */
#define EP_ROWS (B_DIM * T_DIM)       /* 1200 */
#define DP_ROWS (B_DIM * UP1)         /* 324 */
#define NDIAG_B 380                    /* t+u diagonals for lpb */
#define NDIAG_E 379                    /* t+u diagonals for lpe */

typedef float f32x4 __attribute__((ext_vector_type(4)));
typedef short short8 __attribute__((ext_vector_type(8)));
typedef short short4v __attribute__((ext_vector_type(4)));
typedef __bf16 bf16x8 __attribute__((ext_vector_type(8)));

static __device__ __forceinline__ unsigned short f2bf(float f) {
  unsigned int u = __builtin_bit_cast(unsigned int, f);
  return (unsigned short)((u + 0x7fffu + ((u >> 16) & 1u)) >> 16);
}
static __device__ __forceinline__ float fexp(float x) {
  return __builtin_amdgcn_exp2f(x * 1.44269504088896341f);
}
static __device__ __forceinline__ float flog(float x) {
  return __builtin_amdgcn_logf(x) * 0.693147180559945310f;
}
static __device__ __forceinline__ float tanh_fast(float x) {
  float e = __builtin_amdgcn_exp2f(x * 2.88539008177792681f); // exp(2x)
  return 1.0f - 2.0f * __builtin_amdgcn_rcpf(e + 1.0f);
}

// ---------------- Kernel 0: weights fp32 -> bf16 ----------------
__global__ __launch_bounds__(256) void cvt_kernel(
    const float* __restrict__ Wf, const float* __restrict__ Wp,
    short* __restrict__ WfB, short* __restrict__ WpB) {
  int idx = blockIdx.x * 256 + threadIdx.x;
  const int nf = (512 * 640) / 4;   // 81920
  const int np = (V_DIM * NINNER) / 4;
  if (idx < nf) {
    float4 v = ((const float4*)Wf)[idx];
    short4v o;
    o[0] = (short)f2bf(v.x); o[1] = (short)f2bf(v.y);
    o[2] = (short)f2bf(v.z); o[3] = (short)f2bf(v.w);
    ((short4v*)WfB)[idx] = o;
  } else if (idx < nf + np) {
    int j = idx - nf;
    float4 v = ((const float4*)Wp)[j];
    short4v o;
    o[0] = (short)f2bf(v.x); o[1] = (short)f2bf(v.y);
    o[2] = (short)f2bf(v.z); o[3] = (short)f2bf(v.w);
    ((short4v*)WpB)[j] = o;
  }
}

// ---------------- Kernel 1: enc/dec projections (MFMA bf16) ----------------
// grid = 50: bid = ob*2+half. ob<19: ep rows; else dp rows (bf added).
// Each block: 64 rows x 256 cols (half selects col half), 4 waves x 64 cols.
#define EP_BLOCKS 19
__global__ __launch_bounds__(256, 2) void proj_kernel(
    const float* __restrict__ enc, const float* __restrict__ dec,
    const short* __restrict__ WfB, const float* __restrict__ bfv,
    float* __restrict__ ep, float* __restrict__ dp) {
  const int half = blockIdx.x & 1;
  const int ob = blockIdx.x >> 1;
  const bool is_dp = (ob >= EP_BLOCKS);
  const int row0 = (is_dp ? ob - EP_BLOCKS : ob) * 64;
  const int nrows = is_dp ? DP_ROWS : EP_ROWS;
  const float* __restrict__ src = is_dp ? dec : enc;
  const short* __restrict__ wb = WfB + (is_dp ? 320 : 0); // row stride 640
  float* __restrict__ out = is_dp ? dp : ep;

  __shared__ short As[64 * 320];  // 40 KB, XOR-swizzled
  const int tid = threadIdx.x;

  // stage 64 rows x 320 as bf16 (swizzled)
  #pragma unroll
  for (int it = 0; it < 10; ++it) {
    int chunk = it * 256 + tid;        // 2560 chunks of 8 elems
    int m = chunk / 40;
    int c = chunk - m * 40;
    int r = row0 + m;
    short8 hv;
    #pragma unroll
    for (int j = 0; j < 8; ++j) hv[j] = 0;
    if (r < nrows) {
      const float* p = src + (size_t)r * 320 + c * 8;
      float4 a0 = *(const float4*)p;
      float4 a1 = *(const float4*)(p + 4);
      hv[0] = (short)f2bf(a0.x); hv[1] = (short)f2bf(a0.y);
      hv[2] = (short)f2bf(a0.z); hv[3] = (short)f2bf(a0.w);
      hv[4] = (short)f2bf(a1.x); hv[5] = (short)f2bf(a1.y);
      hv[6] = (short)f2bf(a1.z); hv[7] = (short)f2bf(a1.w);
    }
    int off = (m * 640 + c * 16) ^ ((m & 7) << 4);
    *(short8*)((char*)As + off) = hv;
  }
  __syncthreads();

  const int lane = tid & 63, wid = tid >> 6;
  const int lr = lane & 15, g = lane >> 4;

  int lin[4], xm[4];
  #pragma unroll
  for (int mf = 0; mf < 4; ++mf) {
    int row = mf * 16 + lr;
    lin[mf] = row * 640 + g * 16;
    xm[mf] = (row & 7) << 4;
  }

  const int n0 = half * 256 + wid * 64;
  const short* wpc[4];
  float bfc[4];
  #pragma unroll
  for (int nf2 = 0; nf2 < 4; ++nf2) {
    int col = n0 + nf2 * 16 + lr;
    wpc[nf2] = wb + (size_t)col * 640 + g * 8;
    bfc[nf2] = is_dp ? bfv[col] : 0.f;
  }
  f32x4 acc[4][4];
  #pragma unroll
  for (int mf = 0; mf < 4; ++mf)
    #pragma unroll
    for (int nf2 = 0; nf2 < 4; ++nf2)
      acc[mf][nf2] = (f32x4){0.f, 0.f, 0.f, 0.f};

  bf16x8 bcur[4];
  #pragma unroll
  for (int nf2 = 0; nf2 < 4; ++nf2)
    bcur[nf2] = __builtin_bit_cast(bf16x8, *(const short8*)(wpc[nf2]));

  #pragma unroll
  for (int kk = 0; kk < 10; ++kk) {
    bf16x8 av[4], bnx[4];
    #pragma unroll
    for (int mf = 0; mf < 4; ++mf) {
      int off = (lin[mf] + (kk << 6)) ^ xm[mf];
      av[mf] = __builtin_bit_cast(bf16x8, *(const short8*)((const char*)As + off));
    }
    if (kk < 9) {
      #pragma unroll
      for (int nf2 = 0; nf2 < 4; ++nf2)
        bnx[nf2] = __builtin_bit_cast(bf16x8, *(const short8*)(wpc[nf2] + (kk + 1) * 32));
    }
    #pragma unroll
    for (int mf = 0; mf < 4; ++mf)
      #pragma unroll
      for (int nf2 = 0; nf2 < 4; ++nf2)
        acc[mf][nf2] = __builtin_amdgcn_mfma_f32_16x16x32_bf16(av[mf], bcur[nf2], acc[mf][nf2], 0, 0, 0);
    if (kk < 9) {
      #pragma unroll
      for (int nf2 = 0; nf2 < 4; ++nf2) bcur[nf2] = bnx[nf2];
    }
  }
  #pragma unroll
  for (int mf = 0; mf < 4; ++mf)
    #pragma unroll
    for (int nf2 = 0; nf2 < 4; ++nf2)
      #pragma unroll
      for (int rr = 0; rr < 4; ++rr) {
        int rowl = mf * 16 + g * 4 + rr;
        int grow = row0 + rowl;
        if (grow < nrows) {
          int col = n0 + nf2 * 16 + lr;
          out[(size_t)grow * NINNER + col] = acc[mf][nf2][rr] + bfc[nf2];
        }
      }
}

// ---------------- Kernel 2: fused joint + log-softmax slices ----------------
// 512 threads (8 waves), 64 rows x V=1024; wave w owns cols [w*128, w*128+128)
// as 2 subchunks of 64. h = tanh(ep+dp) in swizzled LDS. Fixed-shift softmax
// (logits provably O(1)): plain sum-of-exp, add-butterfly combine.
__global__ __launch_bounds__(512, 4) void joint_kernel(
    const float* __restrict__ ep, const float* __restrict__ dp,
    const short* __restrict__ WpB, const float* __restrict__ bp,
    const int* __restrict__ tgt,
    float* __restrict__ lpb_d, float* __restrict__ lpe_d) {
  extern __shared__ char hbuf[];  // 64 * 512 * 2 = 65536 B
  __shared__ int ep_off[64], dp_off[64], bld_off[64], eld_off[64], tgt_s[64];
  __shared__ float l0_s[64], lt_s[64];
  __shared__ float ws_s[8][64];

  const int tid = threadIdx.x;
  const int row0 = blockIdx.x * 64;

  if (tid < 64) {
    int gr = row0 + tid;
    if (gr < NROWS) {
      int b = gr / (T_DIM * UP1);
      int rem = gr - b * (T_DIM * UP1);
      int t = rem / UP1;
      int u = rem - t * UP1;
      ep_off[tid] = (b * T_DIM + t) * NINNER;
      dp_off[tid] = (b * UP1 + u) * NINNER;
      bld_off[tid] = (b * NDIAG_B + (t + u)) * UP1 + u;          // diag layout
      eld_off[tid] = (u < U_DIM) ? ((b * NDIAG_E + (t + u)) * U_DIM + u) : -1;
      tgt_s[tid] = (u < U_DIM) ? tgt[b * U_DIM + u] : 0;
    } else {
      ep_off[tid] = 0; dp_off[tid] = 0; bld_off[tid] = -1; eld_off[tid] = -1; tgt_s[tid] = 0;
    }
    l0_s[tid] = 0.f; lt_s[tid] = 0.f;
  }
  __syncthreads();

  // Phase A: h into LDS (bf16, swizzled)
  #pragma unroll 2
  for (int it = 0; it < 8; ++it) {
    int chunk = it * 512 + tid;    // 4096 chunks of 8
    int m = chunk >> 6, c = chunk & 63;
    short8 hv;
    #pragma unroll
    for (int j = 0; j < 8; ++j) hv[j] = 0;
    if (bld_off[m] >= 0) {
      const float* pe = ep + ep_off[m] + c * 8;
      const float* pd = dp + dp_off[m] + c * 8;
      float4 e0 = *(const float4*)pe;
      float4 e1 = *(const float4*)(pe + 4);
      float4 d0 = *(const float4*)pd;
      float4 d1 = *(const float4*)(pd + 4);
      hv[0] = (short)f2bf(tanh_fast(e0.x + d0.x));
      hv[1] = (short)f2bf(tanh_fast(e0.y + d0.y));
      hv[2] = (short)f2bf(tanh_fast(e0.z + d0.z));
      hv[3] = (short)f2bf(tanh_fast(e0.w + d0.w));
      hv[4] = (short)f2bf(tanh_fast(e1.x + d1.x));
      hv[5] = (short)f2bf(tanh_fast(e1.y + d1.y));
      hv[6] = (short)f2bf(tanh_fast(e1.z + d1.z));
      hv[7] = (short)f2bf(tanh_fast(e1.w + d1.w));
    }
    int off = ((m << 10) + (c << 4)) ^ ((m & 7) << 4);
    *(short8*)(hbuf + off) = hv;
  }
  __syncthreads();

  const int lane = tid & 63, wid = tid >> 6;
  const int lr = lane & 15, g = lane >> 4;

  int lin[4], xm[4];
  #pragma unroll
  for (int mf = 0; mf < 4; ++mf) {
    int row = mf * 16 + lr;
    lin[mf] = (row << 10) + (g << 4);
    xm[mf] = (row & 7) << 4;
  }
  int tv[4][4];
  #pragma unroll
  for (int mf = 0; mf < 4; ++mf)
    #pragma unroll
    for (int rr = 0; rr < 4; ++rr)
      tv[mf][rr] = tgt_s[mf * 16 + g * 4 + rr];

  float rsum[4][4];
  #pragma unroll
  for (int mf = 0; mf < 4; ++mf)
    #pragma unroll
    for (int rr = 0; rr < 4; ++rr) rsum[mf][rr] = 0.f;

  #pragma unroll
  for (int sc = 0; sc < 2; ++sc) {
    const int n0 = wid * 128 + sc * 64;
    const short* wpc[4];
    float bpv[4];
    #pragma unroll
    for (int nf = 0; nf < 4; ++nf) {
      int col = n0 + nf * 16 + lr;
      wpc[nf] = WpB + (size_t)col * NINNER + g * 8;
      bpv[nf] = bp[col];
    }
    f32x4 acc[4][4];
    #pragma unroll
    for (int mf = 0; mf < 4; ++mf)
      #pragma unroll
      for (int nf = 0; nf < 4; ++nf)
        acc[mf][nf] = (f32x4){0.f, 0.f, 0.f, 0.f};

    bf16x8 bcur[4];
    #pragma unroll
    for (int nf = 0; nf < 4; ++nf)
      bcur[nf] = __builtin_bit_cast(bf16x8, *(const short8*)(wpc[nf]));

    #pragma unroll
    for (int kk = 0; kk < 16; ++kk) {
      bf16x8 av[4], bnx[4];
      #pragma unroll
      for (int mf = 0; mf < 4; ++mf) {
        int off = (lin[mf] + (kk << 6)) ^ xm[mf];
        av[mf] = __builtin_bit_cast(bf16x8, *(const short8*)(hbuf + off));
      }
      if (kk < 15) {
        #pragma unroll
        for (int nf = 0; nf < 4; ++nf)
          bnx[nf] = __builtin_bit_cast(bf16x8, *(const short8*)(wpc[nf] + (kk + 1) * 32));
      }
      #pragma unroll
      for (int mf = 0; mf < 4; ++mf)
        #pragma unroll
        for (int nf = 0; nf < 4; ++nf)
          acc[mf][nf] = __builtin_amdgcn_mfma_f32_16x16x32_bf16(av[mf], bcur[nf], acc[mf][nf], 0, 0, 0);
      if (kk < 15) {
        #pragma unroll
        for (int nf = 0; nf < 4; ++nf) bcur[nf] = bnx[nf];
      }
    }
    // fold: plain sum-of-exp (shift 0) over this 64-col subchunk
    #pragma unroll
    for (int mf = 0; mf < 4; ++mf)
      #pragma unroll
      for (int rr = 0; rr < 4; ++rr) {
        float x0 = acc[mf][0][rr] + bpv[0];
        float x1 = acc[mf][1][rr] + bpv[1];
        float x2 = acc[mf][2][rr] + bpv[2];
        float x3 = acc[mf][3][rr] + bpv[3];
        int rowl = mf * 16 + g * 4 + rr;
        if (wid == 0 && sc == 0 && lr == 0) l0_s[rowl] = x0;  // v = 0
        int dtv = tv[mf][rr] - n0;
        if (dtv >= 0 && dtv < 64 && (dtv & 15) == lr) {
          int nfi = dtv >> 4;
          lt_s[rowl] = (nfi == 0) ? x0 : (nfi == 1) ? x1 : (nfi == 2) ? x2 : x3;
        }
        rsum[mf][rr] += fexp(x0) + fexp(x1) + fexp(x2) + fexp(x3);
      }
  }
  // add-butterfly across the 16 lanes of each group
  #pragma unroll
  for (int mf = 0; mf < 4; ++mf)
    #pragma unroll
    for (int rr = 0; rr < 4; ++rr) {
      float s_ = rsum[mf][rr];
      #pragma unroll
      for (int o = 1; o < 16; o <<= 1) s_ += __shfl_xor(s_, o);
      if (lr == 0) ws_s[wid][mf * 16 + g * 4 + rr] = s_;
    }
  __syncthreads();
  if (tid < 64) {
    int bo = bld_off[tid];
    if (bo >= 0) {
      float S = 0.f;
      #pragma unroll
      for (int w = 0; w < 8; ++w) S += ws_s[w][tid];
      float lse = flog(S);
      lpb_d[bo] = l0_s[tid] - lse;
      int eo = eld_off[tid];
      if (eo >= 0) lpe_d[eo] = lt_s[tid] - lse;
    }
  }
}

// ---------------- Kernel 3: alpha wavefront DP + loss ----------------
// 1 block x 256 threads; wave w owns batch b=w. No __syncthreads in the loop:
// neighbor alpha via shuffles; lp loads are diag-major (coalesced), depth-4
// prefetch ring with static indices (unroll-by-4).
__global__ __launch_bounds__(256) void alpha_kernel(
    const float* __restrict__ lpb_d, const float* __restrict__ lpe_d,
    const int* __restrict__ ilen, const int* __restrict__ ulen_,
    float* __restrict__ out) {
  __shared__ float lls[B_DIM];
  const int tid = threadIdx.x;
  const int b = tid >> 6;
  const int lane = tid & 63;
  const float NEG = -1e30f;
  const int tl = ilen[b], ul = ulen_[b];

  const int u0 = lane;           // slot 0: u = 0..63
  const int u1 = 64 + lane;      // slot 1: u = 64..80 (lane < 17)
  const bool act1 = (u1 <= 80);

  const float* pb = lpb_d + (size_t)b * NDIAG_B * UP1;
  const float* pe = lpe_d + (size_t)b * NDIAG_E * U_DIM;

  float pa0 = (u0 == 0) ? 0.f : NEG;  // alpha on diag 0
  float pa1 = NEG;

  float blr0[4], emr0[4], blr1[4], emr1[4];
  #pragma unroll
  for (int j = 0; j < 4; ++j) {   // step d=j+1 uses diag index dd=j
    int dd = j;
    blr0[j] = pb[dd * UP1 + u0];
    emr0[j] = (u0 >= 1) ? pe[dd * U_DIM + (u0 - 1)] : NEG;
    blr1[j] = act1 ? pb[dd * UP1 + u1] : NEG;
    emr1[j] = act1 ? pe[dd * U_DIM + (u1 - 1)] : NEG;
  }

  float fin = NEG;
  for (int d0 = 1; d0 <= 380; d0 += 4) {
    #pragma unroll
    for (int j = 0; j < 4; ++j) {
      const int d = d0 + j;
      // shuffles read previous-diagonal alpha
      float n0t = __shfl(pa0, (lane + 63) & 63);
      float n1t = __shfl(pa1, (lane + 63) & 63);
      float n0_63 = __shfl(pa0, 63);
      // slot 0
      float v0;
      {
        int t = d - u0;
        bool cell = (t >= 0 && t <= T_DIM - 1);
        float a = (cell && t >= 1) ? pa0 + blr0[j] : NEG;
        float e = (cell && u0 >= 1) ? n0t + emr0[j] : NEG;
        float mx = fmaxf(a, e), mn = fminf(a, e);
        v0 = cell ? mx + flog(1.0f + fexp(mn - mx)) : NEG;
        if (u0 == ul && t == tl - 1) fin = v0;
      }
      // slot 1
      {
        int t = d - u1;
        float nem = (lane == 0) ? n0_63 : n1t;
        bool cell = act1 && (t >= 0 && t <= T_DIM - 1);
        float a = (cell && t >= 1) ? pa1 + blr1[j] : NEG;
        float e = cell ? nem + emr1[j] : NEG;   // u1 >= 64 >= 1 always
        float mx = fmaxf(a, e), mn = fminf(a, e);
        float v1 = cell ? mx + flog(1.0f + fexp(mn - mx)) : NEG;
        if (act1 && u1 == ul && t == tl - 1) fin = v1;
        pa1 = v1;
      }
      pa0 = v0;
      // prefetch for step d+4 (diag index dd = d+3)
      {
        int dd = d + 3;
        bool okb = (dd < NDIAG_B), oke = (dd < NDIAG_E);
        blr0[j] = okb ? pb[dd * UP1 + u0] : NEG;
        emr0[j] = (oke && u0 >= 1) ? pe[dd * U_DIM + (u0 - 1)] : NEG;
        blr1[j] = (okb && act1) ? pb[dd * UP1 + u1] : NEG;
        emr1[j] = (oke && act1) ? pe[dd * U_DIM + (u1 - 1)] : NEG;
      }
    }
  }
  // reduce fin across the wave (only one lane set it)
  #pragma unroll
  for (int o = 32; o; o >>= 1) fin = fmaxf(fin, __shfl_xor(fin, o));
  if (lane == 0) {
    float last = pb[(size_t)(tl - 1 + ul) * UP1 + ul];
    lls[b] = fin + last;
  }
  __syncthreads();
  if (tid == 0)
    out[0] = -(lls[0] + lls[1] + lls[2] + lls[3]) * (1.0f / (float)B_DIM);
}

// ---------------- launcher ----------------
extern "C" void kernel_launch(void* const* d_in, const int* in_sizes, int n_in,
                              void* d_out, int out_size, void* d_ws, size_t ws_size,
                              hipStream_t stream) {
  const float* enc = (const float*)d_in[0];
  const float* dec = (const float*)d_in[1];
  const float* Wf  = (const float*)d_in[2];
  const float* bfv = (const float*)d_in[3];
  const float* Wp  = (const float*)d_in[4];
  const float* bp  = (const float*)d_in[5];
  const int* targets = (const int*)d_in[6];
  const int* ilen    = (const int*)d_in[7];
  const int* ulen    = (const int*)d_in[8];
  float* out = (float*)d_out;
  char* ws = (char*)d_ws;

  short* WfB   = (short*)(ws + 0);          //   655360 B
  short* WpB   = (short*)(ws + 655360);     //  1048576 B
  float* ep    = (float*)(ws + 1703936);    //  2457600 B
  float* dp    = (float*)(ws + 4161536);    //   663552 B
  float* lpb_d = (float*)(ws + 4825088);    //   492480 B (4*380*81)
  float* lpe_d = (float*)(ws + 5317568);    //   485120 B (4*379*80) -> 5802688 B

  cvt_kernel<<<832, 256, 0, stream>>>(Wf, Wp, WfB, WpB);
  proj_kernel<<<50, 256, 0, stream>>>(enc, dec, WfB, bfv, ep, dp);
  joint_kernel<<<(NROWS + 63) / 64, 512, 65536, stream>>>(ep, dp, WpB, bp, targets, lpb_d, lpe_d);
  alpha_kernel<<<1, 256, 0, stream>>>(lpb_d, lpe_d, ilen, ulen, out);
}

// Round 3
// 664.872 us; speedup vs baseline: 1.2944x; 1.2944x over previous
//
#include <hip/hip_runtime.h>

#define B_DIM 4
#define T_DIM 300
#define U_DIM 80
#define UP1   81
#define V_DIM 1024
#define NINNER 512
#define NROWS (B_DIM * T_DIM * UP1)   /* 97200 */
#define EP_ROWS (B_DIM * T_DIM)       /* 1200 */
#define DP_ROWS (B_DIM * UP1)         /* 324 */
#define NDIAG_B 380                    /* t+u diagonals for lpb */
#define NDIAG_E 379                    /* t+u diagonals for lpe */

typedef float f32x4 __attribute__((ext_vector_type(4)));
typedef short short8 __attribute__((ext_vector_type(8)));
typedef short short4v __attribute__((ext_vector_type(4)));
typedef __bf16 bf16x8 __attribute__((ext_vector_type(8)));

static __device__ __forceinline__ unsigned short f2bf(float f) {
  unsigned int u = __builtin_bit_cast(unsigned int, f);
  return (unsigned short)((u + 0x7fffu + ((u >> 16) & 1u)) >> 16);
}
static __device__ __forceinline__ float fexp(float x) {
  return __builtin_amdgcn_exp2f(x * 1.44269504088896341f);
}
static __device__ __forceinline__ float flog(float x) {
  return __builtin_amdgcn_logf(x) * 0.693147180559945310f;
}
static __device__ __forceinline__ float tanh_fast(float x) {
  float e = __builtin_amdgcn_exp2f(x * 2.88539008177792681f); // exp(2x)
  return 1.0f - 2.0f * __builtin_amdgcn_rcpf(e + 1.0f);
}

// ---------------- Kernel 0: weights fp32 -> bf16 ----------------
__global__ __launch_bounds__(256) void cvt_kernel(
    const float* __restrict__ Wf, const float* __restrict__ Wp,
    short* __restrict__ WfB, short* __restrict__ WpB) {
  int idx = blockIdx.x * 256 + threadIdx.x;
  const int nf = (512 * 640) / 4;   // 81920
  const int np = (V_DIM * NINNER) / 4;
  if (idx < nf) {
    float4 v = ((const float4*)Wf)[idx];
    short4v o;
    o[0] = (short)f2bf(v.x); o[1] = (short)f2bf(v.y);
    o[2] = (short)f2bf(v.z); o[3] = (short)f2bf(v.w);
    ((short4v*)WfB)[idx] = o;
  } else if (idx < nf + np) {
    int j = idx - nf;
    float4 v = ((const float4*)Wp)[j];
    short4v o;
    o[0] = (short)f2bf(v.x); o[1] = (short)f2bf(v.y);
    o[2] = (short)f2bf(v.z); o[3] = (short)f2bf(v.w);
    ((short4v*)WpB)[j] = o;
  }
}

// ---------------- Kernel 1: enc/dec projections (MFMA bf16) ----------------
// grid = 50: bid = ob*2+half. ob<19: ep rows; else dp rows (bf added).
#define EP_BLOCKS 19
__global__ __launch_bounds__(256, 2) void proj_kernel(
    const float* __restrict__ enc, const float* __restrict__ dec,
    const short* __restrict__ WfB, const float* __restrict__ bfv,
    float* __restrict__ ep, float* __restrict__ dp) {
  const int half = blockIdx.x & 1;
  const int ob = blockIdx.x >> 1;
  const bool is_dp = (ob >= EP_BLOCKS);
  const int row0 = (is_dp ? ob - EP_BLOCKS : ob) * 64;
  const int nrows = is_dp ? DP_ROWS : EP_ROWS;
  const float* __restrict__ src = is_dp ? dec : enc;
  const short* __restrict__ wb = WfB + (is_dp ? 320 : 0); // row stride 640
  float* __restrict__ out = is_dp ? dp : ep;

  __shared__ short As[64 * 320];  // 40 KB, XOR-swizzled
  const int tid = threadIdx.x;

  #pragma unroll
  for (int it = 0; it < 10; ++it) {
    int chunk = it * 256 + tid;        // 2560 chunks of 8 elems
    int m = chunk / 40;
    int c = chunk - m * 40;
    int r = row0 + m;
    short8 hv;
    #pragma unroll
    for (int j = 0; j < 8; ++j) hv[j] = 0;
    if (r < nrows) {
      const float* p = src + (size_t)r * 320 + c * 8;
      float4 a0 = *(const float4*)p;
      float4 a1 = *(const float4*)(p + 4);
      hv[0] = (short)f2bf(a0.x); hv[1] = (short)f2bf(a0.y);
      hv[2] = (short)f2bf(a0.z); hv[3] = (short)f2bf(a0.w);
      hv[4] = (short)f2bf(a1.x); hv[5] = (short)f2bf(a1.y);
      hv[6] = (short)f2bf(a1.z); hv[7] = (short)f2bf(a1.w);
    }
    int off = (m * 640 + c * 16) ^ ((m & 7) << 4);
    *(short8*)((char*)As + off) = hv;
  }
  __syncthreads();

  const int lane = tid & 63, wid = tid >> 6;
  const int lr = lane & 15, g = lane >> 4;

  int lin[4], xm[4];
  #pragma unroll
  for (int mf = 0; mf < 4; ++mf) {
    int row = mf * 16 + lr;
    lin[mf] = row * 640 + g * 16;
    xm[mf] = (row & 7) << 4;
  }

  const int n0 = half * 256 + wid * 64;
  const short* wpc[4];
  float bfc[4];
  #pragma unroll
  for (int nf2 = 0; nf2 < 4; ++nf2) {
    int col = n0 + nf2 * 16 + lr;
    wpc[nf2] = wb + (size_t)col * 640 + g * 8;
    bfc[nf2] = is_dp ? bfv[col] : 0.f;
  }
  f32x4 acc[4][4];
  #pragma unroll
  for (int mf = 0; mf < 4; ++mf)
    #pragma unroll
    for (int nf2 = 0; nf2 < 4; ++nf2)
      acc[mf][nf2] = (f32x4){0.f, 0.f, 0.f, 0.f};

  bf16x8 bcur[4];
  #pragma unroll
  for (int nf2 = 0; nf2 < 4; ++nf2)
    bcur[nf2] = __builtin_bit_cast(bf16x8, *(const short8*)(wpc[nf2]));

  #pragma unroll
  for (int kk = 0; kk < 10; ++kk) {
    bf16x8 av[4], bnx[4];
    #pragma unroll
    for (int mf = 0; mf < 4; ++mf) {
      int off = (lin[mf] + (kk << 6)) ^ xm[mf];
      av[mf] = __builtin_bit_cast(bf16x8, *(const short8*)((const char*)As + off));
    }
    if (kk < 9) {
      #pragma unroll
      for (int nf2 = 0; nf2 < 4; ++nf2)
        bnx[nf2] = __builtin_bit_cast(bf16x8, *(const short8*)(wpc[nf2] + (kk + 1) * 32));
    }
    #pragma unroll
    for (int mf = 0; mf < 4; ++mf)
      #pragma unroll
      for (int nf2 = 0; nf2 < 4; ++nf2)
        acc[mf][nf2] = __builtin_amdgcn_mfma_f32_16x16x32_bf16(av[mf], bcur[nf2], acc[mf][nf2], 0, 0, 0);
    if (kk < 9) {
      #pragma unroll
      for (int nf2 = 0; nf2 < 4; ++nf2) bcur[nf2] = bnx[nf2];
    }
  }
  #pragma unroll
  for (int mf = 0; mf < 4; ++mf)
    #pragma unroll
    for (int nf2 = 0; nf2 < 4; ++nf2)
      #pragma unroll
      for (int rr = 0; rr < 4; ++rr) {
        int rowl = mf * 16 + g * 4 + rr;
        int grow = row0 + rowl;
        if (grow < nrows) {
          int col = n0 + nf2 * 16 + lr;
          out[(size_t)grow * NINNER + col] = acc[mf][nf2][rr] + bfc[nf2];
        }
      }
}

// ---------------- Kernel 2: fused joint + log-softmax slices ----------------
// 256 threads (4 waves), 32 rows x V=1024; wave w owns cols [w*256, w*256+256)
// as 4 subchunks of 64. h = tanh(ep+dp) in swizzled LDS (32 KB -> 4 blocks/CU).
// Fixed-shift softmax (logits provably O(1)): plain sum-of-exp.
#define JROWS 32
__global__ __launch_bounds__(256, 4) void joint_kernel(
    const float* __restrict__ ep, const float* __restrict__ dp,
    const short* __restrict__ WpB, const float* __restrict__ bp,
    const int* __restrict__ tgt,
    float* __restrict__ lpb_d, float* __restrict__ lpe_d) {
  extern __shared__ char hbuf[];  // 32 * 512 * 2 = 32768 B
  __shared__ int ep_off[JROWS], dp_off[JROWS], bld_off[JROWS], eld_off[JROWS], tgt_s[JROWS];
  __shared__ float l0_s[JROWS], lt_s[JROWS];
  __shared__ float ws_s[4][JROWS];

  const int tid = threadIdx.x;
  const int row0 = blockIdx.x * JROWS;

  if (tid < JROWS) {
    int gr = row0 + tid;
    if (gr < NROWS) {
      int b = gr / (T_DIM * UP1);
      int rem = gr - b * (T_DIM * UP1);
      int t = rem / UP1;
      int u = rem - t * UP1;
      ep_off[tid] = (b * T_DIM + t) * NINNER;
      dp_off[tid] = (b * UP1 + u) * NINNER;
      bld_off[tid] = (b * NDIAG_B + (t + u)) * UP1 + u;          // diag layout
      eld_off[tid] = (u < U_DIM) ? ((b * NDIAG_E + (t + u)) * U_DIM + u) : -1;
      tgt_s[tid] = (u < U_DIM) ? tgt[b * U_DIM + u] : 0;
    } else {
      ep_off[tid] = 0; dp_off[tid] = 0; bld_off[tid] = -1; eld_off[tid] = -1; tgt_s[tid] = 0;
    }
    l0_s[tid] = 0.f; lt_s[tid] = 0.f;
  }
  __syncthreads();

  // Phase A: h into LDS (bf16, swizzled)
  #pragma unroll 2
  for (int it = 0; it < 8; ++it) {
    int chunk = it * 256 + tid;    // 2048 chunks of 8
    int m = chunk >> 6, c = chunk & 63;
    short8 hv;
    #pragma unroll
    for (int j = 0; j < 8; ++j) hv[j] = 0;
    if (bld_off[m] >= 0) {
      const float* pe = ep + ep_off[m] + c * 8;
      const float* pd = dp + dp_off[m] + c * 8;
      float4 e0 = *(const float4*)pe;
      float4 e1 = *(const float4*)(pe + 4);
      float4 d0 = *(const float4*)pd;
      float4 d1 = *(const float4*)(pd + 4);
      hv[0] = (short)f2bf(tanh_fast(e0.x + d0.x));
      hv[1] = (short)f2bf(tanh_fast(e0.y + d0.y));
      hv[2] = (short)f2bf(tanh_fast(e0.z + d0.z));
      hv[3] = (short)f2bf(tanh_fast(e0.w + d0.w));
      hv[4] = (short)f2bf(tanh_fast(e1.x + d1.x));
      hv[5] = (short)f2bf(tanh_fast(e1.y + d1.y));
      hv[6] = (short)f2bf(tanh_fast(e1.z + d1.z));
      hv[7] = (short)f2bf(tanh_fast(e1.w + d1.w));
    }
    int off = ((m << 10) + (c << 4)) ^ ((m & 7) << 4);
    *(short8*)(hbuf + off) = hv;
  }
  __syncthreads();

  const int lane = tid & 63, wid = tid >> 6;
  const int lr = lane & 15, g = lane >> 4;

  int lin[2], xm[2];
  #pragma unroll
  for (int mf = 0; mf < 2; ++mf) {
    int row = mf * 16 + lr;
    lin[mf] = (row << 10) + (g << 4);
    xm[mf] = (row & 7) << 4;
  }
  int tv[2][4];
  #pragma unroll
  for (int mf = 0; mf < 2; ++mf)
    #pragma unroll
    for (int rr = 0; rr < 4; ++rr)
      tv[mf][rr] = tgt_s[mf * 16 + g * 4 + rr];

  float rsum[2][4];
  #pragma unroll
  for (int mf = 0; mf < 2; ++mf)
    #pragma unroll
    for (int rr = 0; rr < 4; ++rr) rsum[mf][rr] = 0.f;

  #pragma unroll
  for (int sc = 0; sc < 4; ++sc) {
    const int n0 = wid * 256 + sc * 64;
    const short* wpc[4];
    float bpv[4];
    #pragma unroll
    for (int nf = 0; nf < 4; ++nf) {
      int col = n0 + nf * 16 + lr;
      wpc[nf] = WpB + (size_t)col * NINNER + g * 8;
      bpv[nf] = bp[col];
    }
    f32x4 acc[2][4];
    #pragma unroll
    for (int mf = 0; mf < 2; ++mf)
      #pragma unroll
      for (int nf = 0; nf < 4; ++nf)
        acc[mf][nf] = (f32x4){0.f, 0.f, 0.f, 0.f};

    bf16x8 bcur[4];
    #pragma unroll
    for (int nf = 0; nf < 4; ++nf)
      bcur[nf] = __builtin_bit_cast(bf16x8, *(const short8*)(wpc[nf]));

    #pragma unroll
    for (int kk = 0; kk < 16; ++kk) {
      bf16x8 av[2], bnx[4];
      #pragma unroll
      for (int mf = 0; mf < 2; ++mf) {
        int off = (lin[mf] + (kk << 6)) ^ xm[mf];
        av[mf] = __builtin_bit_cast(bf16x8, *(const short8*)(hbuf + off));
      }
      if (kk < 15) {
        #pragma unroll
        for (int nf = 0; nf < 4; ++nf)
          bnx[nf] = __builtin_bit_cast(bf16x8, *(const short8*)(wpc[nf] + (kk + 1) * 32));
      }
      #pragma unroll
      for (int mf = 0; mf < 2; ++mf)
        #pragma unroll
        for (int nf = 0; nf < 4; ++nf)
          acc[mf][nf] = __builtin_amdgcn_mfma_f32_16x16x32_bf16(av[mf], bcur[nf], acc[mf][nf], 0, 0, 0);
      if (kk < 15) {
        #pragma unroll
        for (int nf = 0; nf < 4; ++nf) bcur[nf] = bnx[nf];
      }
    }
    // fold: plain sum-of-exp (shift 0) over this 64-col subchunk
    #pragma unroll
    for (int mf = 0; mf < 2; ++mf)
      #pragma unroll
      for (int rr = 0; rr < 4; ++rr) {
        float x0 = acc[mf][0][rr] + bpv[0];
        float x1 = acc[mf][1][rr] + bpv[1];
        float x2 = acc[mf][2][rr] + bpv[2];
        float x3 = acc[mf][3][rr] + bpv[3];
        int rowl = mf * 16 + g * 4 + rr;
        if (wid == 0 && sc == 0 && lr == 0) l0_s[rowl] = x0;  // v = 0
        int dtv = tv[mf][rr] - n0;
        if (dtv >= 0 && dtv < 64 && (dtv & 15) == lr) {
          int nfi = dtv >> 4;
          lt_s[rowl] = (nfi == 0) ? x0 : (nfi == 1) ? x1 : (nfi == 2) ? x2 : x3;
        }
        rsum[mf][rr] += fexp(x0) + fexp(x1) + fexp(x2) + fexp(x3);
      }
  }
  // add-butterfly across the 16 lanes of each group
  #pragma unroll
  for (int mf = 0; mf < 2; ++mf)
    #pragma unroll
    for (int rr = 0; rr < 4; ++rr) {
      float s_ = rsum[mf][rr];
      #pragma unroll
      for (int o = 1; o < 16; o <<= 1) s_ += __shfl_xor(s_, o);
      if (lr == 0) ws_s[wid][mf * 16 + g * 4 + rr] = s_;
    }
  __syncthreads();
  if (tid < JROWS) {
    int bo = bld_off[tid];
    if (bo >= 0) {
      float S = ws_s[0][tid] + ws_s[1][tid] + ws_s[2][tid] + ws_s[3][tid];
      float lse = flog(S);
      lpb_d[bo] = l0_s[tid] - lse;
      int eo = eld_off[tid];
      if (eo >= 0) lpe_d[eo] = lt_s[tid] - lse;
    }
  }
}

// ---------------- Kernel 3: alpha wavefront DP + loss ----------------
// 1 block x 256 threads; wave w owns batch b=w. No __syncthreads in the loop:
// neighbor alpha via shuffles; lp loads are diag-major (coalesced), depth-4
// prefetch ring with static indices (unroll-by-4).
__global__ __launch_bounds__(256) void alpha_kernel(
    const float* __restrict__ lpb_d, const float* __restrict__ lpe_d,
    const int* __restrict__ ilen, const int* __restrict__ ulen_,
    float* __restrict__ out) {
  __shared__ float lls[B_DIM];
  const int tid = threadIdx.x;
  const int b = tid >> 6;
  const int lane = tid & 63;
  const float NEG = -1e30f;
  const int tl = ilen[b], ul = ulen_[b];

  const int u0 = lane;           // slot 0: u = 0..63
  const int u1 = 64 + lane;      // slot 1: u = 64..80 (lane < 17)
  const bool act1 = (u1 <= 80);

  const float* pb = lpb_d + (size_t)b * NDIAG_B * UP1;
  const float* pe = lpe_d + (size_t)b * NDIAG_E * U_DIM;

  float pa0 = (u0 == 0) ? 0.f : NEG;  // alpha on diag 0
  float pa1 = NEG;

  float blr0[4], emr0[4], blr1[4], emr1[4];
  #pragma unroll
  for (int j = 0; j < 4; ++j) {   // step d=j+1 uses diag index dd=j
    int dd = j;
    blr0[j] = pb[dd * UP1 + u0];
    emr0[j] = (u0 >= 1) ? pe[dd * U_DIM + (u0 - 1)] : NEG;
    blr1[j] = act1 ? pb[dd * UP1 + u1] : NEG;
    emr1[j] = act1 ? pe[dd * U_DIM + (u1 - 1)] : NEG;
  }

  float fin = NEG;
  for (int d0 = 1; d0 <= 380; d0 += 4) {
    #pragma unroll
    for (int j = 0; j < 4; ++j) {
      const int d = d0 + j;
      float n0t = __shfl(pa0, (lane + 63) & 63);
      float n1t = __shfl(pa1, (lane + 63) & 63);
      float n0_63 = __shfl(pa0, 63);
      // slot 0
      float v0;
      {
        int t = d - u0;
        bool cell = (t >= 0 && t <= T_DIM - 1);
        float a = (cell && t >= 1) ? pa0 + blr0[j] : NEG;
        float e = (cell && u0 >= 1) ? n0t + emr0[j] : NEG;
        float mx = fmaxf(a, e), mn = fminf(a, e);
        v0 = cell ? mx + flog(1.0f + fexp(mn - mx)) : NEG;
        if (u0 == ul && t == tl - 1) fin = v0;
      }
      // slot 1
      {
        int t = d - u1;
        float nem = (lane == 0) ? n0_63 : n1t;
        bool cell = act1 && (t >= 0 && t <= T_DIM - 1);
        float a = (cell && t >= 1) ? pa1 + blr1[j] : NEG;
        float e = cell ? nem + emr1[j] : NEG;   // u1 >= 64 >= 1 always
        float mx = fmaxf(a, e), mn = fminf(a, e);
        float v1 = cell ? mx + flog(1.0f + fexp(mn - mx)) : NEG;
        if (act1 && u1 == ul && t == tl - 1) fin = v1;
        pa1 = v1;
      }
      pa0 = v0;
      // prefetch for step d+4 (diag index dd = d+3)
      {
        int dd = d + 3;
        bool okb = (dd < NDIAG_B), oke = (dd < NDIAG_E);
        blr0[j] = okb ? pb[dd * UP1 + u0] : NEG;
        emr0[j] = (oke && u0 >= 1) ? pe[dd * U_DIM + (u0 - 1)] : NEG;
        blr1[j] = (okb && act1) ? pb[dd * UP1 + u1] : NEG;
        emr1[j] = (oke && act1) ? pe[dd * U_DIM + (u1 - 1)] : NEG;
      }
    }
  }
  // reduce fin across the wave (only one lane set it)
  #pragma unroll
  for (int o = 32; o; o >>= 1) fin = fmaxf(fin, __shfl_xor(fin, o));
  if (lane == 0) {
    float last = pb[(size_t)(tl - 1 + ul) * UP1 + ul];
    lls[b] = fin + last;
  }
  __syncthreads();
  if (tid == 0)
    out[0] = -(lls[0] + lls[1] + lls[2] + lls[3]) * (1.0f / (float)B_DIM);
}

// ---------------- launcher ----------------
extern "C" void kernel_launch(void* const* d_in, const int* in_sizes, int n_in,
                              void* d_out, int out_size, void* d_ws, size_t ws_size,
                              hipStream_t stream) {
  const float* enc = (const float*)d_in[0];
  const float* dec = (const float*)d_in[1];
  const float* Wf  = (const float*)d_in[2];
  const float* bfv = (const float*)d_in[3];
  const float* Wp  = (const float*)d_in[4];
  const float* bp  = (const float*)d_in[5];
  const int* targets = (const int*)d_in[6];
  const int* ilen    = (const int*)d_in[7];
  const int* ulen    = (const int*)d_in[8];
  float* out = (float*)d_out;
  char* ws = (char*)d_ws;

  short* WfB   = (short*)(ws + 0);          //   655360 B
  short* WpB   = (short*)(ws + 655360);     //  1048576 B
  float* ep    = (float*)(ws + 1703936);    //  2457600 B
  float* dp    = (float*)(ws + 4161536);    //   663552 B
  float* lpb_d = (float*)(ws + 4825088);    //   492480 B (4*380*81)
  float* lpe_d = (float*)(ws + 5317568);    //   485120 B (4*379*80) -> 5802688 B

  cvt_kernel<<<832, 256, 0, stream>>>(Wf, Wp, WfB, WpB);
  proj_kernel<<<50, 256, 0, stream>>>(enc, dec, WfB, bfv, ep, dp);
  joint_kernel<<<(NROWS + JROWS - 1) / JROWS, 256, 32768, stream>>>(ep, dp, WpB, bp, targets, lpb_d, lpe_d);
  alpha_kernel<<<1, 256, 0, stream>>>(lpb_d, lpe_d, ilen, ulen, out);
}

// Round 4
// 540.091 us; speedup vs baseline: 1.5935x; 1.2310x over previous
//
#include <hip/hip_runtime.h>

#define B_DIM 4
#define T_DIM 300
#define U_DIM 80
#define UP1   81
#define V_DIM 1024
#define NINNER 512
#define NROWS (B_DIM * T_DIM * UP1)   /* 97200 */
#define EP_ROWS (B_DIM * T_DIM)       /* 1200 */
#define DP_ROWS (B_DIM * UP1)         /* 324 */
#define NDIAG_B 380                    /* t+u diagonals for lpb */
#define NDIAG_E 379                    /* t+u diagonals for lpe */

typedef float f32x4 __attribute__((ext_vector_type(4)));
typedef short short8 __attribute__((ext_vector_type(8)));
typedef short short4v __attribute__((ext_vector_type(4)));
typedef __bf16 bf16x8 __attribute__((ext_vector_type(8)));

static __device__ __forceinline__ unsigned short f2bf(float f) {
  unsigned int u = __builtin_bit_cast(unsigned int, f);
  return (unsigned short)((u + 0x7fffu + ((u >> 16) & 1u)) >> 16);
}
static __device__ __forceinline__ float fexp(float x) {
  return __builtin_amdgcn_exp2f(x * 1.44269504088896341f);
}
static __device__ __forceinline__ float flog(float x) {
  return __builtin_amdgcn_logf(x) * 0.693147180559945310f;
}
static __device__ __forceinline__ float tanh_fast(float x) {
  float e = __builtin_amdgcn_exp2f(x * 2.88539008177792681f); // exp(2x)
  return 1.0f - 2.0f * __builtin_amdgcn_rcpf(e + 1.0f);
}

// ---------------- Kernel 0: weights fp32 -> bf16 ----------------
__global__ __launch_bounds__(256) void cvt_kernel(
    const float* __restrict__ Wf, const float* __restrict__ Wp,
    short* __restrict__ WfB, short* __restrict__ WpB) {
  int idx = blockIdx.x * 256 + threadIdx.x;
  const int nf = (512 * 640) / 4;   // 81920
  const int np = (V_DIM * NINNER) / 4;
  if (idx < nf) {
    float4 v = ((const float4*)Wf)[idx];
    short4v o;
    o[0] = (short)f2bf(v.x); o[1] = (short)f2bf(v.y);
    o[2] = (short)f2bf(v.z); o[3] = (short)f2bf(v.w);
    ((short4v*)WfB)[idx] = o;
  } else if (idx < nf + np) {
    int j = idx - nf;
    float4 v = ((const float4*)Wp)[j];
    short4v o;
    o[0] = (short)f2bf(v.x); o[1] = (short)f2bf(v.y);
    o[2] = (short)f2bf(v.z); o[3] = (short)f2bf(v.w);
    ((short4v*)WpB)[j] = o;
  }
}

// ---------------- Kernel 1: enc/dec projections (MFMA bf16) ----------------
// grid = 50: bid = ob*2+half. ob<19: ep rows; else dp rows (bf added).
// NOTE: no min-waves arg on launch_bounds — with MFMA kernels, min-waves>=4
// makes hipcc split the unified file (Arch 64 / AGPR 64) and spill (r2/r3).
#define EP_BLOCKS 19
__global__ __launch_bounds__(256) void proj_kernel(
    const float* __restrict__ enc, const float* __restrict__ dec,
    const short* __restrict__ WfB, const float* __restrict__ bfv,
    float* __restrict__ ep, float* __restrict__ dp) {
  const int half = blockIdx.x & 1;
  const int ob = blockIdx.x >> 1;
  const bool is_dp = (ob >= EP_BLOCKS);
  const int row0 = (is_dp ? ob - EP_BLOCKS : ob) * 64;
  const int nrows = is_dp ? DP_ROWS : EP_ROWS;
  const float* __restrict__ src = is_dp ? dec : enc;
  const short* __restrict__ wb = WfB + (is_dp ? 320 : 0); // row stride 640
  float* __restrict__ out = is_dp ? dp : ep;

  __shared__ short As[64 * 320];  // 40 KB, XOR-swizzled
  const int tid = threadIdx.x;

  #pragma unroll
  for (int it = 0; it < 10; ++it) {
    int chunk = it * 256 + tid;        // 2560 chunks of 8 elems
    int m = chunk / 40;
    int c = chunk - m * 40;
    int r = row0 + m;
    short8 hv;
    #pragma unroll
    for (int j = 0; j < 8; ++j) hv[j] = 0;
    if (r < nrows) {
      const float* p = src + (size_t)r * 320 + c * 8;
      float4 a0 = *(const float4*)p;
      float4 a1 = *(const float4*)(p + 4);
      hv[0] = (short)f2bf(a0.x); hv[1] = (short)f2bf(a0.y);
      hv[2] = (short)f2bf(a0.z); hv[3] = (short)f2bf(a0.w);
      hv[4] = (short)f2bf(a1.x); hv[5] = (short)f2bf(a1.y);
      hv[6] = (short)f2bf(a1.z); hv[7] = (short)f2bf(a1.w);
    }
    int off = (m * 640 + c * 16) ^ ((m & 7) << 4);
    *(short8*)((char*)As + off) = hv;
  }
  __syncthreads();

  const int lane = tid & 63, wid = tid >> 6;
  const int lr = lane & 15, g = lane >> 4;

  int lin[4], xm[4];
  #pragma unroll
  for (int mf = 0; mf < 4; ++mf) {
    int row = mf * 16 + lr;
    lin[mf] = row * 640 + g * 16;
    xm[mf] = (row & 7) << 4;
  }

  const int n0 = half * 256 + wid * 64;
  const short* wpc[4];
  float bfc[4];
  #pragma unroll
  for (int nf2 = 0; nf2 < 4; ++nf2) {
    int col = n0 + nf2 * 16 + lr;
    wpc[nf2] = wb + (size_t)col * 640 + g * 8;
    bfc[nf2] = is_dp ? bfv[col] : 0.f;
  }
  f32x4 acc[4][4];
  #pragma unroll
  for (int mf = 0; mf < 4; ++mf)
    #pragma unroll
    for (int nf2 = 0; nf2 < 4; ++nf2)
      acc[mf][nf2] = (f32x4){0.f, 0.f, 0.f, 0.f};

  #pragma unroll 2
  for (int kk = 0; kk < 10; ++kk) {
    bf16x8 av[4], bv[4];
    #pragma unroll
    for (int mf = 0; mf < 4; ++mf) {
      int off = (lin[mf] + (kk << 6)) ^ xm[mf];
      av[mf] = __builtin_bit_cast(bf16x8, *(const short8*)((const char*)As + off));
    }
    #pragma unroll
    for (int nf2 = 0; nf2 < 4; ++nf2)
      bv[nf2] = __builtin_bit_cast(bf16x8, *(const short8*)(wpc[nf2] + kk * 32));
    #pragma unroll
    for (int mf = 0; mf < 4; ++mf)
      #pragma unroll
      for (int nf2 = 0; nf2 < 4; ++nf2)
        acc[mf][nf2] = __builtin_amdgcn_mfma_f32_16x16x32_bf16(av[mf], bv[nf2], acc[mf][nf2], 0, 0, 0);
  }
  #pragma unroll
  for (int mf = 0; mf < 4; ++mf)
    #pragma unroll
    for (int nf2 = 0; nf2 < 4; ++nf2)
      #pragma unroll
      for (int rr = 0; rr < 4; ++rr) {
        int rowl = mf * 16 + g * 4 + rr;
        int grow = row0 + rowl;
        if (grow < nrows) {
          int col = n0 + nf2 * 16 + lr;
          out[(size_t)grow * NINNER + col] = acc[mf][nf2][rr] + bfc[nf2];
        }
      }
}

// ---------------- Kernel 2: fused joint + log-softmax slices ----------------
// 256 threads (4 waves), 32 rows x V=1024; wave w owns cols [w*256, w*256+256)
// as 4 subchunks of 64. h = tanh(ep+dp) in swizzled LDS (32 KB -> 4 blocks/CU
// via LDS; VGPR ~92 keeps 16 waves/CU). Fixed-shift softmax: plain sum-of-exp.
// NOTE: __launch_bounds__(256) ONLY — see proj_kernel note (spill r2/r3).
#define JROWS 32
__global__ __launch_bounds__(256) void joint_kernel(
    const float* __restrict__ ep, const float* __restrict__ dp,
    const short* __restrict__ WpB, const float* __restrict__ bp,
    const int* __restrict__ tgt,
    float* __restrict__ lpb_d, float* __restrict__ lpe_d) {
  extern __shared__ char hbuf[];  // 32 * 512 * 2 = 32768 B
  __shared__ int ep_off[JROWS], dp_off[JROWS], bld_off[JROWS], eld_off[JROWS], tgt_s[JROWS];
  __shared__ float l0_s[JROWS], lt_s[JROWS];
  __shared__ float ws_s[4][JROWS];

  const int tid = threadIdx.x;
  const int row0 = blockIdx.x * JROWS;

  if (tid < JROWS) {
    int gr = row0 + tid;
    if (gr < NROWS) {
      int b = gr / (T_DIM * UP1);
      int rem = gr - b * (T_DIM * UP1);
      int t = rem / UP1;
      int u = rem - t * UP1;
      ep_off[tid] = (b * T_DIM + t) * NINNER;
      dp_off[tid] = (b * UP1 + u) * NINNER;
      bld_off[tid] = (b * NDIAG_B + (t + u)) * UP1 + u;          // diag layout
      eld_off[tid] = (u < U_DIM) ? ((b * NDIAG_E + (t + u)) * U_DIM + u) : -1;
      tgt_s[tid] = (u < U_DIM) ? tgt[b * U_DIM + u] : 0;
    } else {
      ep_off[tid] = 0; dp_off[tid] = 0; bld_off[tid] = -1; eld_off[tid] = -1; tgt_s[tid] = 0;
    }
    l0_s[tid] = 0.f; lt_s[tid] = 0.f;
  }
  __syncthreads();

  // Phase A: h into LDS (bf16, swizzled)
  #pragma unroll 2
  for (int it = 0; it < 8; ++it) {
    int chunk = it * 256 + tid;    // 2048 chunks of 8
    int m = chunk >> 6, c = chunk & 63;
    short8 hv;
    #pragma unroll
    for (int j = 0; j < 8; ++j) hv[j] = 0;
    if (bld_off[m] >= 0) {
      const float* pe = ep + ep_off[m] + c * 8;
      const float* pd = dp + dp_off[m] + c * 8;
      float4 e0 = *(const float4*)pe;
      float4 e1 = *(const float4*)(pe + 4);
      float4 d0 = *(const float4*)pd;
      float4 d1 = *(const float4*)(pd + 4);
      hv[0] = (short)f2bf(tanh_fast(e0.x + d0.x));
      hv[1] = (short)f2bf(tanh_fast(e0.y + d0.y));
      hv[2] = (short)f2bf(tanh_fast(e0.z + d0.z));
      hv[3] = (short)f2bf(tanh_fast(e0.w + d0.w));
      hv[4] = (short)f2bf(tanh_fast(e1.x + d1.x));
      hv[5] = (short)f2bf(tanh_fast(e1.y + d1.y));
      hv[6] = (short)f2bf(tanh_fast(e1.z + d1.z));
      hv[7] = (short)f2bf(tanh_fast(e1.w + d1.w));
    }
    int off = ((m << 10) + (c << 4)) ^ ((m & 7) << 4);
    *(short8*)(hbuf + off) = hv;
  }
  __syncthreads();

  const int lane = tid & 63, wid = tid >> 6;
  const int lr = lane & 15, g = lane >> 4;

  int lin[2], xm[2];
  #pragma unroll
  for (int mf = 0; mf < 2; ++mf) {
    int row = mf * 16 + lr;
    lin[mf] = (row << 10) + (g << 4);
    xm[mf] = (row & 7) << 4;
  }
  int tv[2][4];
  #pragma unroll
  for (int mf = 0; mf < 2; ++mf)
    #pragma unroll
    for (int rr = 0; rr < 4; ++rr)
      tv[mf][rr] = tgt_s[mf * 16 + g * 4 + rr];

  float rsum[2][4];
  #pragma unroll
  for (int mf = 0; mf < 2; ++mf)
    #pragma unroll
    for (int rr = 0; rr < 4; ++rr) rsum[mf][rr] = 0.f;

  #pragma unroll
  for (int sc = 0; sc < 4; ++sc) {
    const int n0 = wid * 256 + sc * 64;
    const short* wpc[4];
    float bpv[4];
    #pragma unroll
    for (int nf = 0; nf < 4; ++nf) {
      int col = n0 + nf * 16 + lr;
      wpc[nf] = WpB + (size_t)col * NINNER + g * 8;
      bpv[nf] = bp[col];
    }
    f32x4 acc[2][4];
    #pragma unroll
    for (int mf = 0; mf < 2; ++mf)
      #pragma unroll
      for (int nf = 0; nf < 4; ++nf)
        acc[mf][nf] = (f32x4){0.f, 0.f, 0.f, 0.f};

    #pragma unroll 2
    for (int kk = 0; kk < 16; ++kk) {
      bf16x8 av[2], bv[4];
      #pragma unroll
      for (int mf = 0; mf < 2; ++mf) {
        int off = (lin[mf] + (kk << 6)) ^ xm[mf];
        av[mf] = __builtin_bit_cast(bf16x8, *(const short8*)(hbuf + off));
      }
      #pragma unroll
      for (int nf = 0; nf < 4; ++nf)
        bv[nf] = __builtin_bit_cast(bf16x8, *(const short8*)(wpc[nf] + kk * 32));
      #pragma unroll
      for (int mf = 0; mf < 2; ++mf)
        #pragma unroll
        for (int nf = 0; nf < 4; ++nf)
          acc[mf][nf] = __builtin_amdgcn_mfma_f32_16x16x32_bf16(av[mf], bv[nf], acc[mf][nf], 0, 0, 0);
    }
    // fold: plain sum-of-exp (shift 0) over this 64-col subchunk
    #pragma unroll
    for (int mf = 0; mf < 2; ++mf)
      #pragma unroll
      for (int rr = 0; rr < 4; ++rr) {
        float x0 = acc[mf][0][rr] + bpv[0];
        float x1 = acc[mf][1][rr] + bpv[1];
        float x2 = acc[mf][2][rr] + bpv[2];
        float x3 = acc[mf][3][rr] + bpv[3];
        int rowl = mf * 16 + g * 4 + rr;
        if (wid == 0 && sc == 0 && lr == 0) l0_s[rowl] = x0;  // v = 0
        int dtv = tv[mf][rr] - n0;
        if (dtv >= 0 && dtv < 64 && (dtv & 15) == lr) {
          int nfi = dtv >> 4;
          lt_s[rowl] = (nfi == 0) ? x0 : (nfi == 1) ? x1 : (nfi == 2) ? x2 : x3;
        }
        rsum[mf][rr] += fexp(x0) + fexp(x1) + fexp(x2) + fexp(x3);
      }
  }
  // add-butterfly across the 16 lanes of each group
  #pragma unroll
  for (int mf = 0; mf < 2; ++mf)
    #pragma unroll
    for (int rr = 0; rr < 4; ++rr) {
      float s_ = rsum[mf][rr];
      #pragma unroll
      for (int o = 1; o < 16; o <<= 1) s_ += __shfl_xor(s_, o);
      if (lr == 0) ws_s[wid][mf * 16 + g * 4 + rr] = s_;
    }
  __syncthreads();
  if (tid < JROWS) {
    int bo = bld_off[tid];
    if (bo >= 0) {
      float S = ws_s[0][tid] + ws_s[1][tid] + ws_s[2][tid] + ws_s[3][tid];
      float lse = flog(S);
      lpb_d[bo] = l0_s[tid] - lse;
      int eo = eld_off[tid];
      if (eo >= 0) lpe_d[eo] = lt_s[tid] - lse;
    }
  }
}

// ---------------- Kernel 3: alpha wavefront DP + loss ----------------
// 1 block x 256 threads; wave w owns batch b=w. No __syncthreads in the loop:
// neighbor alpha via shuffles; lp loads are diag-major (coalesced), depth-4
// prefetch ring with static indices (unroll-by-4).
__global__ __launch_bounds__(256) void alpha_kernel(
    const float* __restrict__ lpb_d, const float* __restrict__ lpe_d,
    const int* __restrict__ ilen, const int* __restrict__ ulen_,
    float* __restrict__ out) {
  __shared__ float lls[B_DIM];
  const int tid = threadIdx.x;
  const int b = tid >> 6;
  const int lane = tid & 63;
  const float NEG = -1e30f;
  const int tl = ilen[b], ul = ulen_[b];

  const int u0 = lane;           // slot 0: u = 0..63
  const int u1 = 64 + lane;      // slot 1: u = 64..80 (lane < 17)
  const bool act1 = (u1 <= 80);

  const float* pb = lpb_d + (size_t)b * NDIAG_B * UP1;
  const float* pe = lpe_d + (size_t)b * NDIAG_E * U_DIM;

  float pa0 = (u0 == 0) ? 0.f : NEG;  // alpha on diag 0
  float pa1 = NEG;

  float blr0[4], emr0[4], blr1[4], emr1[4];
  #pragma unroll
  for (int j = 0; j < 4; ++j) {   // step d=j+1 uses diag index dd=j
    int dd = j;
    blr0[j] = pb[dd * UP1 + u0];
    emr0[j] = (u0 >= 1) ? pe[dd * U_DIM + (u0 - 1)] : NEG;
    blr1[j] = act1 ? pb[dd * UP1 + u1] : NEG;
    emr1[j] = act1 ? pe[dd * U_DIM + (u1 - 1)] : NEG;
  }

  float fin = NEG;
  for (int d0 = 1; d0 <= 380; d0 += 4) {
    #pragma unroll
    for (int j = 0; j < 4; ++j) {
      const int d = d0 + j;
      float n0t = __shfl(pa0, (lane + 63) & 63);
      float n1t = __shfl(pa1, (lane + 63) & 63);
      float n0_63 = __shfl(pa0, 63);
      // slot 0
      float v0;
      {
        int t = d - u0;
        bool cell = (t >= 0 && t <= T_DIM - 1);
        float a = (cell && t >= 1) ? pa0 + blr0[j] : NEG;
        float e = (cell && u0 >= 1) ? n0t + emr0[j] : NEG;
        float mx = fmaxf(a, e), mn = fminf(a, e);
        v0 = cell ? mx + flog(1.0f + fexp(mn - mx)) : NEG;
        if (u0 == ul && t == tl - 1) fin = v0;
      }
      // slot 1
      {
        int t = d - u1;
        float nem = (lane == 0) ? n0_63 : n1t;
        bool cell = act1 && (t >= 0 && t <= T_DIM - 1);
        float a = (cell && t >= 1) ? pa1 + blr1[j] : NEG;
        float e = cell ? nem + emr1[j] : NEG;   // u1 >= 64 >= 1 always
        float mx = fmaxf(a, e), mn = fminf(a, e);
        float v1 = cell ? mx + flog(1.0f + fexp(mn - mx)) : NEG;
        if (act1 && u1 == ul && t == tl - 1) fin = v1;
        pa1 = v1;
      }
      pa0 = v0;
      // prefetch for step d+4 (diag index dd = d+3)
      {
        int dd = d + 3;
        bool okb = (dd < NDIAG_B), oke = (dd < NDIAG_E);
        blr0[j] = okb ? pb[dd * UP1 + u0] : NEG;
        emr0[j] = (oke && u0 >= 1) ? pe[dd * U_DIM + (u0 - 1)] : NEG;
        blr1[j] = (okb && act1) ? pb[dd * UP1 + u1] : NEG;
        emr1[j] = (oke && act1) ? pe[dd * U_DIM + (u1 - 1)] : NEG;
      }
    }
  }
  // reduce fin across the wave (only one lane set it)
  #pragma unroll
  for (int o = 32; o; o >>= 1) fin = fmaxf(fin, __shfl_xor(fin, o));
  if (lane == 0) {
    float last = pb[(size_t)(tl - 1 + ul) * UP1 + ul];
    lls[b] = fin + last;
  }
  __syncthreads();
  if (tid == 0)
    out[0] = -(lls[0] + lls[1] + lls[2] + lls[3]) * (1.0f / (float)B_DIM);
}

// ---------------- launcher ----------------
extern "C" void kernel_launch(void* const* d_in, const int* in_sizes, int n_in,
                              void* d_out, int out_size, void* d_ws, size_t ws_size,
                              hipStream_t stream) {
  const float* enc = (const float*)d_in[0];
  const float* dec = (const float*)d_in[1];
  const float* Wf  = (const float*)d_in[2];
  const float* bfv = (const float*)d_in[3];
  const float* Wp  = (const float*)d_in[4];
  const float* bp  = (const float*)d_in[5];
  const int* targets = (const int*)d_in[6];
  const int* ilen    = (const int*)d_in[7];
  const int* ulen    = (const int*)d_in[8];
  float* out = (float*)d_out;
  char* ws = (char*)d_ws;

  short* WfB   = (short*)(ws + 0);          //   655360 B
  short* WpB   = (short*)(ws + 655360);     //  1048576 B
  float* ep    = (float*)(ws + 1703936);    //  2457600 B
  float* dp    = (float*)(ws + 4161536);    //   663552 B
  float* lpb_d = (float*)(ws + 4825088);    //   492480 B (4*380*81)
  float* lpe_d = (float*)(ws + 5317568);    //   485120 B (4*379*80) -> 5802688 B

  cvt_kernel<<<832, 256, 0, stream>>>(Wf, Wp, WfB, WpB);
  proj_kernel<<<50, 256, 0, stream>>>(enc, dec, WfB, bfv, ep, dp);
  joint_kernel<<<(NROWS + JROWS - 1) / JROWS, 256, 32768, stream>>>(ep, dp, WpB, bp, targets, lpb_d, lpe_d);
  alpha_kernel<<<1, 256, 0, stream>>>(lpb_d, lpe_d, ilen, ulen, out);
}

// Round 5
// 303.628 us; speedup vs baseline: 2.8344x; 1.7788x over previous
//
#include <hip/hip_runtime.h>

#define B_DIM 4
#define T_DIM 300
#define U_DIM 80
#define UP1   81
#define V_DIM 1024
#define NINNER 512
#define NROWS (B_DIM * T_DIM * UP1)   /* 97200 */
#define EP_ROWS (B_DIM * T_DIM)       /* 1200 */
#define DP_ROWS (B_DIM * UP1)         /* 324 */
#define NDIAG_B 380                    /* t+u diagonals for lpb */
#define NDIAG_E 379                    /* t+u diagonals for lpe */
#define WF_PART 163840                 /* 512 cols x 320 k, per half of Wf */

typedef float f32x4 __attribute__((ext_vector_type(4)));
typedef short short8 __attribute__((ext_vector_type(8)));
typedef short short4v __attribute__((ext_vector_type(4)));
typedef __bf16 bf16x8 __attribute__((ext_vector_type(8)));

static __device__ __forceinline__ unsigned short f2bf(float f) {
  unsigned int u = __builtin_bit_cast(unsigned int, f);
  return (unsigned short)((u + 0x7fffu + ((u >> 16) & 1u)) >> 16);
}
static __device__ __forceinline__ float fexp(float x) {
  return __builtin_amdgcn_exp2f(x * 1.44269504088896341f);
}
static __device__ __forceinline__ float flog(float x) {
  return __builtin_amdgcn_logf(x) * 0.693147180559945310f;
}
static __device__ __forceinline__ float tanh_fast(float x) {
  float e = __builtin_amdgcn_exp2f(x * 2.88539008177792681f); // exp(2x)
  return 1.0f - 2.0f * __builtin_amdgcn_rcpf(e + 1.0f);
}

// ---------------- Kernel 0: weights fp32 -> bf16, MFMA-frag-linear pack -----
// B-matrix element (c,k) -> frag=(c>>4)*KB+(k>>5); lane=((k>>3)&3)*16+(c&15);
// offset = frag*512 + lane*8 + (k&7). A B-fragment load is then lane-linear:
// one coalesced 1 KB global_load_dwordx4 (fixes r4's 16-line scatter).
__global__ __launch_bounds__(256) void cvt_kernel(
    const float* __restrict__ Wf, const float* __restrict__ Wp,
    short* __restrict__ WfB, short* __restrict__ WpB) {
  int idx = blockIdx.x * 256 + threadIdx.x;
  const int nf = (512 * 640) / 4;   // 81920
  const int np = (V_DIM * NINNER) / 4;
  if (idx < nf) {
    float4 v = ((const float4*)Wf)[idx];
    int flat = idx * 4;
    int c = flat / 640;
    int kc = flat - c * 640;
    int part = (kc >= 320);
    int k0 = kc - (part ? 320 : 0);
    int dest = (part ? WF_PART : 0)
             + ((c >> 4) * 10 + (k0 >> 5)) * 512
             + (((k0 >> 3) & 3) * 16 + (c & 15)) * 8 + (k0 & 7);
    short4v o;
    o[0] = (short)f2bf(v.x); o[1] = (short)f2bf(v.y);
    o[2] = (short)f2bf(v.z); o[3] = (short)f2bf(v.w);
    *(short4v*)(WfB + dest) = o;
  } else if (idx < nf + np) {
    int j = idx - nf;
    float4 v = ((const float4*)Wp)[j];
    int flat = j * 4;
    int c = flat >> 9;
    int k0 = flat & 511;
    int dest = ((c >> 4) * 16 + (k0 >> 5)) * 512
             + (((k0 >> 3) & 3) * 16 + (c & 15)) * 8 + (k0 & 7);
    short4v o;
    o[0] = (short)f2bf(v.x); o[1] = (short)f2bf(v.y);
    o[2] = (short)f2bf(v.z); o[3] = (short)f2bf(v.w);
    *(short4v*)(WpB + dest) = o;
  }
}

// ---------------- Kernel 1: enc/dec projections (MFMA bf16) ----------------
// grid = 50: bid = ob*2+half. ob<19: ep rows; else dp rows (bf added).
// NOTE: no min-waves arg — min-waves>=4 on MFMA kernels splits the unified
// RF (Arch 64 / AGPR 64) and spills (r2/r3).
#define EP_BLOCKS 19
__global__ __launch_bounds__(256) void proj_kernel(
    const float* __restrict__ enc, const float* __restrict__ dec,
    const short* __restrict__ WfB, const float* __restrict__ bfv,
    float* __restrict__ ep, float* __restrict__ dp) {
  const int half = blockIdx.x & 1;
  const int ob = blockIdx.x >> 1;
  const bool is_dp = (ob >= EP_BLOCKS);
  const int row0 = (is_dp ? ob - EP_BLOCKS : ob) * 64;
  const int nrows = is_dp ? DP_ROWS : EP_ROWS;
  const float* __restrict__ src = is_dp ? dec : enc;
  const short* __restrict__ bb = WfB + (is_dp ? WF_PART : 0);  // packed
  float* __restrict__ out = is_dp ? dp : ep;

  __shared__ short As[64 * 320];  // 40 KB, XOR-swizzled
  const int tid = threadIdx.x;

  #pragma unroll
  for (int it = 0; it < 10; ++it) {
    int chunk = it * 256 + tid;        // 2560 chunks of 8 elems
    int m = chunk / 40;
    int c = chunk - m * 40;
    int r = row0 + m;
    short8 hv;
    #pragma unroll
    for (int j = 0; j < 8; ++j) hv[j] = 0;
    if (r < nrows) {
      const float* p = src + (size_t)r * 320 + c * 8;
      float4 a0 = *(const float4*)p;
      float4 a1 = *(const float4*)(p + 4);
      hv[0] = (short)f2bf(a0.x); hv[1] = (short)f2bf(a0.y);
      hv[2] = (short)f2bf(a0.z); hv[3] = (short)f2bf(a0.w);
      hv[4] = (short)f2bf(a1.x); hv[5] = (short)f2bf(a1.y);
      hv[6] = (short)f2bf(a1.z); hv[7] = (short)f2bf(a1.w);
    }
    int off = (m * 640 + c * 16) ^ ((m & 7) << 4);
    *(short8*)((char*)As + off) = hv;
  }
  __syncthreads();

  const int lane = tid & 63, wid = tid >> 6;
  const int lr = lane & 15, g = lane >> 4;

  int lin[4], xm[4];
  #pragma unroll
  for (int mf = 0; mf < 4; ++mf) {
    int row = mf * 16 + lr;
    lin[mf] = row * 640 + g * 16;
    xm[mf] = (row & 7) << 4;
  }

  const int n0 = half * 256 + wid * 64;
  const short* bptr[4];
  float bfc[4];
  #pragma unroll
  for (int nf2 = 0; nf2 < 4; ++nf2) {
    bptr[nf2] = bb + (n0 / 16 + nf2) * 5120 + lane * 8;   // frag-linear
    bfc[nf2] = is_dp ? bfv[n0 + nf2 * 16 + lr] : 0.f;
  }
  f32x4 acc[4][4];
  #pragma unroll
  for (int mf = 0; mf < 4; ++mf)
    #pragma unroll
    for (int nf2 = 0; nf2 < 4; ++nf2)
      acc[mf][nf2] = (f32x4){0.f, 0.f, 0.f, 0.f};

  #pragma unroll 2
  for (int kk = 0; kk < 10; ++kk) {
    bf16x8 av[4], bv[4];
    #pragma unroll
    for (int mf = 0; mf < 4; ++mf) {
      int off = (lin[mf] + (kk << 6)) ^ xm[mf];
      av[mf] = __builtin_bit_cast(bf16x8, *(const short8*)((const char*)As + off));
    }
    #pragma unroll
    for (int nf2 = 0; nf2 < 4; ++nf2)
      bv[nf2] = __builtin_bit_cast(bf16x8, *(const short8*)(bptr[nf2] + kk * 512));
    #pragma unroll
    for (int mf = 0; mf < 4; ++mf)
      #pragma unroll
      for (int nf2 = 0; nf2 < 4; ++nf2)
        acc[mf][nf2] = __builtin_amdgcn_mfma_f32_16x16x32_bf16(av[mf], bv[nf2], acc[mf][nf2], 0, 0, 0);
  }
  #pragma unroll
  for (int mf = 0; mf < 4; ++mf)
    #pragma unroll
    for (int nf2 = 0; nf2 < 4; ++nf2)
      #pragma unroll
      for (int rr = 0; rr < 4; ++rr) {
        int rowl = mf * 16 + g * 4 + rr;
        int grow = row0 + rowl;
        if (grow < nrows) {
          int col = n0 + nf2 * 16 + lr;
          out[(size_t)grow * NINNER + col] = acc[mf][nf2][rr] + bfc[nf2];
        }
      }
}

// ---------------- Kernel 2: fused joint + log-softmax slices ----------------
// 512 threads (8 waves), 64 rows x V=1024; wave w owns cols [w*128,(w+1)*128)
// as 2 subchunks of 64; mf=4 -> each B-frag feeds 4 MFMA (halves L2 B-traffic
// vs r4). B reads are frag-linear coalesced. LDS 64 KB -> 2 blocks/CU,
// 16 waves/CU nominal. Fixed-shift softmax: plain sum-of-exp.
#define JROWS 64
__global__ __launch_bounds__(512) void joint_kernel(
    const float* __restrict__ ep, const float* __restrict__ dp,
    const short* __restrict__ WpB, const float* __restrict__ bp,
    const int* __restrict__ tgt,
    float* __restrict__ lpb_d, float* __restrict__ lpe_d) {
  extern __shared__ char hbuf[];  // 64 * 512 * 2 = 65536 B
  __shared__ int ep_off[JROWS], dp_off[JROWS], bld_off[JROWS], eld_off[JROWS], tgt_s[JROWS];
  __shared__ float l0_s[JROWS], lt_s[JROWS];
  __shared__ float ws_s[8][JROWS];

  const int tid = threadIdx.x;
  const int row0 = blockIdx.x * JROWS;

  if (tid < JROWS) {
    int gr = row0 + tid;
    if (gr < NROWS) {
      int b = gr / (T_DIM * UP1);
      int rem = gr - b * (T_DIM * UP1);
      int t = rem / UP1;
      int u = rem - t * UP1;
      ep_off[tid] = (b * T_DIM + t) * NINNER;
      dp_off[tid] = (b * UP1 + u) * NINNER;
      bld_off[tid] = (b * NDIAG_B + (t + u)) * UP1 + u;          // diag layout
      eld_off[tid] = (u < U_DIM) ? ((b * NDIAG_E + (t + u)) * U_DIM + u) : -1;
      tgt_s[tid] = (u < U_DIM) ? tgt[b * U_DIM + u] : 0;
    } else {
      ep_off[tid] = 0; dp_off[tid] = 0; bld_off[tid] = -1; eld_off[tid] = -1; tgt_s[tid] = 0;
    }
    l0_s[tid] = 0.f; lt_s[tid] = 0.f;
  }
  __syncthreads();

  // Phase A: h into LDS (bf16, swizzled)
  #pragma unroll 2
  for (int it = 0; it < 8; ++it) {
    int chunk = it * 512 + tid;    // 4096 chunks of 8
    int m = chunk >> 6, c = chunk & 63;
    short8 hv;
    #pragma unroll
    for (int j = 0; j < 8; ++j) hv[j] = 0;
    if (bld_off[m] >= 0) {
      const float* pe = ep + ep_off[m] + c * 8;
      const float* pd = dp + dp_off[m] + c * 8;
      float4 e0 = *(const float4*)pe;
      float4 e1 = *(const float4*)(pe + 4);
      float4 d0 = *(const float4*)pd;
      float4 d1 = *(const float4*)(pd + 4);
      hv[0] = (short)f2bf(tanh_fast(e0.x + d0.x));
      hv[1] = (short)f2bf(tanh_fast(e0.y + d0.y));
      hv[2] = (short)f2bf(tanh_fast(e0.z + d0.z));
      hv[3] = (short)f2bf(tanh_fast(e0.w + d0.w));
      hv[4] = (short)f2bf(tanh_fast(e1.x + d1.x));
      hv[5] = (short)f2bf(tanh_fast(e1.y + d1.y));
      hv[6] = (short)f2bf(tanh_fast(e1.z + d1.z));
      hv[7] = (short)f2bf(tanh_fast(e1.w + d1.w));
    }
    int off = ((m << 10) + (c << 4)) ^ ((m & 7) << 4);
    *(short8*)(hbuf + off) = hv;
  }
  __syncthreads();

  const int lane = tid & 63, wid = tid >> 6;
  const int lr = lane & 15, g = lane >> 4;

  int lin[4], xm[4];
  #pragma unroll
  for (int mf = 0; mf < 4; ++mf) {
    int row = mf * 16 + lr;
    lin[mf] = (row << 10) + (g << 4);
    xm[mf] = (row & 7) << 4;
  }
  int tv[4][4];
  #pragma unroll
  for (int mf = 0; mf < 4; ++mf)
    #pragma unroll
    for (int rr = 0; rr < 4; ++rr)
      tv[mf][rr] = tgt_s[mf * 16 + g * 4 + rr];

  float rsum[4][4];
  #pragma unroll
  for (int mf = 0; mf < 4; ++mf)
    #pragma unroll
    for (int rr = 0; rr < 4; ++rr) rsum[mf][rr] = 0.f;

  #pragma unroll
  for (int sc = 0; sc < 2; ++sc) {
    const int n0 = wid * 128 + sc * 64;
    const short* bptr[4];
    float bpv[4];
    #pragma unroll
    for (int nf = 0; nf < 4; ++nf) {
      bptr[nf] = WpB + (n0 / 16 + nf) * 8192 + lane * 8;   // frag-linear
      bpv[nf] = bp[n0 + nf * 16 + lr];
    }
    f32x4 acc[4][4];
    #pragma unroll
    for (int mf = 0; mf < 4; ++mf)
      #pragma unroll
      for (int nf = 0; nf < 4; ++nf)
        acc[mf][nf] = (f32x4){0.f, 0.f, 0.f, 0.f};

    #pragma unroll 2
    for (int kk = 0; kk < 16; ++kk) {
      bf16x8 av[4], bv[4];
      #pragma unroll
      for (int mf = 0; mf < 4; ++mf) {
        int off = (lin[mf] + (kk << 6)) ^ xm[mf];
        av[mf] = __builtin_bit_cast(bf16x8, *(const short8*)(hbuf + off));
      }
      #pragma unroll
      for (int nf = 0; nf < 4; ++nf)
        bv[nf] = __builtin_bit_cast(bf16x8, *(const short8*)(bptr[nf] + kk * 512));
      #pragma unroll
      for (int mf = 0; mf < 4; ++mf)
        #pragma unroll
        for (int nf = 0; nf < 4; ++nf)
          acc[mf][nf] = __builtin_amdgcn_mfma_f32_16x16x32_bf16(av[mf], bv[nf], acc[mf][nf], 0, 0, 0);
    }
    // fold: plain sum-of-exp (shift 0) over this 64-col subchunk
    #pragma unroll
    for (int mf = 0; mf < 4; ++mf)
      #pragma unroll
      for (int rr = 0; rr < 4; ++rr) {
        float x0 = acc[mf][0][rr] + bpv[0];
        float x1 = acc[mf][1][rr] + bpv[1];
        float x2 = acc[mf][2][rr] + bpv[2];
        float x3 = acc[mf][3][rr] + bpv[3];
        int rowl = mf * 16 + g * 4 + rr;
        if (wid == 0 && sc == 0 && lr == 0) l0_s[rowl] = x0;  // v = 0
        int dtv = tv[mf][rr] - n0;
        if (dtv >= 0 && dtv < 64 && (dtv & 15) == lr) {
          int nfi = dtv >> 4;
          lt_s[rowl] = (nfi == 0) ? x0 : (nfi == 1) ? x1 : (nfi == 2) ? x2 : x3;
        }
        rsum[mf][rr] += fexp(x0) + fexp(x1) + fexp(x2) + fexp(x3);
      }
  }
  // add-butterfly across the 16 lanes of each group
  #pragma unroll
  for (int mf = 0; mf < 4; ++mf)
    #pragma unroll
    for (int rr = 0; rr < 4; ++rr) {
      float s_ = rsum[mf][rr];
      #pragma unroll
      for (int o = 1; o < 16; o <<= 1) s_ += __shfl_xor(s_, o);
      if (lr == 0) ws_s[wid][mf * 16 + g * 4 + rr] = s_;
    }
  __syncthreads();
  if (tid < JROWS) {
    int bo = bld_off[tid];
    if (bo >= 0) {
      float S = 0.f;
      #pragma unroll
      for (int w = 0; w < 8; ++w) S += ws_s[w][tid];
      float lse = flog(S);
      lpb_d[bo] = l0_s[tid] - lse;
      int eo = eld_off[tid];
      if (eo >= 0) lpe_d[eo] = lt_s[tid] - lse;
    }
  }
}

// ---------------- Kernel 3: alpha wavefront DP + loss ----------------
// 1 block x 256 threads; wave w owns batch b=w. No __syncthreads in the loop:
// neighbor alpha via shuffles; lp loads are diag-major (coalesced), depth-4
// prefetch ring with static indices (unroll-by-4).
__global__ __launch_bounds__(256) void alpha_kernel(
    const float* __restrict__ lpb_d, const float* __restrict__ lpe_d,
    const int* __restrict__ ilen, const int* __restrict__ ulen_,
    float* __restrict__ out) {
  __shared__ float lls[B_DIM];
  const int tid = threadIdx.x;
  const int b = tid >> 6;
  const int lane = tid & 63;
  const float NEG = -1e30f;
  const int tl = ilen[b], ul = ulen_[b];

  const int u0 = lane;           // slot 0: u = 0..63
  const int u1 = 64 + lane;      // slot 1: u = 64..80 (lane < 17)
  const bool act1 = (u1 <= 80);

  const float* pb = lpb_d + (size_t)b * NDIAG_B * UP1;
  const float* pe = lpe_d + (size_t)b * NDIAG_E * U_DIM;

  float pa0 = (u0 == 0) ? 0.f : NEG;  // alpha on diag 0
  float pa1 = NEG;

  float blr0[4], emr0[4], blr1[4], emr1[4];
  #pragma unroll
  for (int j = 0; j < 4; ++j) {   // step d=j+1 uses diag index dd=j
    int dd = j;
    blr0[j] = pb[dd * UP1 + u0];
    emr0[j] = (u0 >= 1) ? pe[dd * U_DIM + (u0 - 1)] : NEG;
    blr1[j] = act1 ? pb[dd * UP1 + u1] : NEG;
    emr1[j] = act1 ? pe[dd * U_DIM + (u1 - 1)] : NEG;
  }

  float fin = NEG;
  for (int d0 = 1; d0 <= 380; d0 += 4) {
    #pragma unroll
    for (int j = 0; j < 4; ++j) {
      const int d = d0 + j;
      float n0t = __shfl(pa0, (lane + 63) & 63);
      float n1t = __shfl(pa1, (lane + 63) & 63);
      float n0_63 = __shfl(pa0, 63);
      // slot 0
      float v0;
      {
        int t = d - u0;
        bool cell = (t >= 0 && t <= T_DIM - 1);
        float a = (cell && t >= 1) ? pa0 + blr0[j] : NEG;
        float e = (cell && u0 >= 1) ? n0t + emr0[j] : NEG;
        float mx = fmaxf(a, e), mn = fminf(a, e);
        v0 = cell ? mx + flog(1.0f + fexp(mn - mx)) : NEG;
        if (u0 == ul && t == tl - 1) fin = v0;
      }
      // slot 1
      {
        int t = d - u1;
        float nem = (lane == 0) ? n0_63 : n1t;
        bool cell = act1 && (t >= 0 && t <= T_DIM - 1);
        float a = (cell && t >= 1) ? pa1 + blr1[j] : NEG;
        float e = cell ? nem + emr1[j] : NEG;   // u1 >= 64 >= 1 always
        float mx = fmaxf(a, e), mn = fminf(a, e);
        float v1 = cell ? mx + flog(1.0f + fexp(mn - mx)) : NEG;
        if (act1 && u1 == ul && t == tl - 1) fin = v1;
        pa1 = v1;
      }
      pa0 = v0;
      // prefetch for step d+4 (diag index dd = d+3)
      {
        int dd = d + 3;
        bool okb = (dd < NDIAG_B), oke = (dd < NDIAG_E);
        blr0[j] = okb ? pb[dd * UP1 + u0] : NEG;
        emr0[j] = (oke && u0 >= 1) ? pe[dd * U_DIM + (u0 - 1)] : NEG;
        blr1[j] = (okb && act1) ? pb[dd * UP1 + u1] : NEG;
        emr1[j] = (oke && act1) ? pe[dd * U_DIM + (u1 - 1)] : NEG;
      }
    }
  }
  // reduce fin across the wave (only one lane set it)
  #pragma unroll
  for (int o = 32; o; o >>= 1) fin = fmaxf(fin, __shfl_xor(fin, o));
  if (lane == 0) {
    float last = pb[(size_t)(tl - 1 + ul) * UP1 + ul];
    lls[b] = fin + last;
  }
  __syncthreads();
  if (tid == 0)
    out[0] = -(lls[0] + lls[1] + lls[2] + lls[3]) * (1.0f / (float)B_DIM);
}

// ---------------- launcher ----------------
extern "C" void kernel_launch(void* const* d_in, const int* in_sizes, int n_in,
                              void* d_out, int out_size, void* d_ws, size_t ws_size,
                              hipStream_t stream) {
  const float* enc = (const float*)d_in[0];
  const float* dec = (const float*)d_in[1];
  const float* Wf  = (const float*)d_in[2];
  const float* bfv = (const float*)d_in[3];
  const float* Wp  = (const float*)d_in[4];
  const float* bp  = (const float*)d_in[5];
  const int* targets = (const int*)d_in[6];
  const int* ilen    = (const int*)d_in[7];
  const int* ulen    = (const int*)d_in[8];
  float* out = (float*)d_out;
  char* ws = (char*)d_ws;

  short* WfB   = (short*)(ws + 0);          //   655360 B (packed)
  short* WpB   = (short*)(ws + 655360);     //  1048576 B (packed)
  float* ep    = (float*)(ws + 1703936);    //  2457600 B
  float* dp    = (float*)(ws + 4161536);    //   663552 B
  float* lpb_d = (float*)(ws + 4825088);    //   492480 B (4*380*81)
  float* lpe_d = (float*)(ws + 5317568);    //   485120 B (4*379*80) -> 5802688 B

  cvt_kernel<<<832, 256, 0, stream>>>(Wf, Wp, WfB, WpB);
  proj_kernel<<<50, 256, 0, stream>>>(enc, dec, WfB, bfv, ep, dp);
  joint_kernel<<<(NROWS + JROWS - 1) / JROWS, 512, 65536, stream>>>(ep, dp, WpB, bp, targets, lpb_d, lpe_d);
  alpha_kernel<<<1, 256, 0, stream>>>(lpb_d, lpe_d, ilen, ulen, out);
}

// Round 6
// 253.659 us; speedup vs baseline: 3.3928x; 1.1970x over previous
//
#include <hip/hip_runtime.h>

#define B_DIM 4
#define T_DIM 300
#define U_DIM 80
#define UP1   81
#define V_DIM 1024
#define NINNER 512
#define NROWS (B_DIM * T_DIM * UP1)   /* 97200 */
#define EP_ROWS (B_DIM * T_DIM)       /* 1200 */
#define DP_ROWS (B_DIM * UP1)         /* 324 */
#define NDIAG_B 380                    /* t+u diagonals for lpb */
#define NDIAG_E 379                    /* t+u diagonals for lpe */
#define WF_PART 163840                 /* 512 cols x 320 k, per half of Wf */

typedef float f32x4 __attribute__((ext_vector_type(4)));
typedef short short8 __attribute__((ext_vector_type(8)));
typedef short short4v __attribute__((ext_vector_type(4)));
typedef __bf16 bf16x8 __attribute__((ext_vector_type(8)));

static __device__ __forceinline__ unsigned short f2bf(float f) {
  unsigned int u = __builtin_bit_cast(unsigned int, f);
  return (unsigned short)((u + 0x7fffu + ((u >> 16) & 1u)) >> 16);
}
static __device__ __forceinline__ float fexp(float x) {
  return __builtin_amdgcn_exp2f(x * 1.44269504088896341f);
}
static __device__ __forceinline__ float flog(float x) {
  return __builtin_amdgcn_logf(x) * 0.693147180559945310f;
}
static __device__ __forceinline__ float tanh_fast(float x) {
  float e = __builtin_amdgcn_exp2f(x * 2.88539008177792681f); // exp(2x)
  return 1.0f - 2.0f * __builtin_amdgcn_rcpf(e + 1.0f);
}

// ---------------- Kernel 0: weights fp32 -> bf16, MFMA-frag-linear pack -----
// B-matrix element (c,k) -> frag=(c>>4)*KB+(k>>5); lane=((k>>3)&3)*16+(c&15);
// offset = frag*512 + lane*8 + (k&7). A B-fragment load is then lane-linear:
// one coalesced 1 KB global_load_dwordx4 (fixes r4's 16-line scatter).
__global__ __launch_bounds__(256) void cvt_kernel(
    const float* __restrict__ Wf, const float* __restrict__ Wp,
    short* __restrict__ WfB, short* __restrict__ WpB) {
  int idx = blockIdx.x * 256 + threadIdx.x;
  const int nf = (512 * 640) / 4;   // 81920
  const int np = (V_DIM * NINNER) / 4;
  if (idx < nf) {
    float4 v = ((const float4*)Wf)[idx];
    int flat = idx * 4;
    int c = flat / 640;
    int kc = flat - c * 640;
    int part = (kc >= 320);
    int k0 = kc - (part ? 320 : 0);
    int dest = (part ? WF_PART : 0)
             + ((c >> 4) * 10 + (k0 >> 5)) * 512
             + (((k0 >> 3) & 3) * 16 + (c & 15)) * 8 + (k0 & 7);
    short4v o;
    o[0] = (short)f2bf(v.x); o[1] = (short)f2bf(v.y);
    o[2] = (short)f2bf(v.z); o[3] = (short)f2bf(v.w);
    *(short4v*)(WfB + dest) = o;
  } else if (idx < nf + np) {
    int j = idx - nf;
    float4 v = ((const float4*)Wp)[j];
    int flat = j * 4;
    int c = flat >> 9;
    int k0 = flat & 511;
    int dest = ((c >> 4) * 16 + (k0 >> 5)) * 512
             + (((k0 >> 3) & 3) * 16 + (c & 15)) * 8 + (k0 & 7);
    short4v o;
    o[0] = (short)f2bf(v.x); o[1] = (short)f2bf(v.y);
    o[2] = (short)f2bf(v.z); o[3] = (short)f2bf(v.w);
    *(short4v*)(WpB + dest) = o;
  }
}

// ---------------- Kernel 1: enc/dec projections (MFMA bf16) ----------------
// grid = 50: bid = ob*2+half. ob<19: ep rows; else dp rows (bf added).
// NOTE: no min-waves arg — min-waves>=4 on MFMA kernels splits the unified
// RF (Arch 64 / AGPR 64) and spills (r2/r3).
#define EP_BLOCKS 19
__global__ __launch_bounds__(256) void proj_kernel(
    const float* __restrict__ enc, const float* __restrict__ dec,
    const short* __restrict__ WfB, const float* __restrict__ bfv,
    float* __restrict__ ep, float* __restrict__ dp) {
  const int half = blockIdx.x & 1;
  const int ob = blockIdx.x >> 1;
  const bool is_dp = (ob >= EP_BLOCKS);
  const int row0 = (is_dp ? ob - EP_BLOCKS : ob) * 64;
  const int nrows = is_dp ? DP_ROWS : EP_ROWS;
  const float* __restrict__ src = is_dp ? dec : enc;
  const short* __restrict__ bb = WfB + (is_dp ? WF_PART : 0);  // packed
  float* __restrict__ out = is_dp ? dp : ep;

  __shared__ short As[64 * 320];  // 40 KB, XOR-swizzled
  const int tid = threadIdx.x;

  #pragma unroll
  for (int it = 0; it < 10; ++it) {
    int chunk = it * 256 + tid;        // 2560 chunks of 8 elems
    int m = chunk / 40;
    int c = chunk - m * 40;
    int r = row0 + m;
    short8 hv;
    #pragma unroll
    for (int j = 0; j < 8; ++j) hv[j] = 0;
    if (r < nrows) {
      const float* p = src + (size_t)r * 320 + c * 8;
      float4 a0 = *(const float4*)p;
      float4 a1 = *(const float4*)(p + 4);
      hv[0] = (short)f2bf(a0.x); hv[1] = (short)f2bf(a0.y);
      hv[2] = (short)f2bf(a0.z); hv[3] = (short)f2bf(a0.w);
      hv[4] = (short)f2bf(a1.x); hv[5] = (short)f2bf(a1.y);
      hv[6] = (short)f2bf(a1.z); hv[7] = (short)f2bf(a1.w);
    }
    int off = (m * 640 + c * 16) ^ ((m & 7) << 4);
    *(short8*)((char*)As + off) = hv;
  }
  __syncthreads();

  const int lane = tid & 63, wid = tid >> 6;
  const int lr = lane & 15, g = lane >> 4;

  int lin[4], xm[4];
  #pragma unroll
  for (int mf = 0; mf < 4; ++mf) {
    int row = mf * 16 + lr;
    lin[mf] = row * 640 + g * 16;
    xm[mf] = (row & 7) << 4;
  }

  const int n0 = half * 256 + wid * 64;
  const short* bptr[4];
  float bfc[4];
  #pragma unroll
  for (int nf2 = 0; nf2 < 4; ++nf2) {
    bptr[nf2] = bb + (n0 / 16 + nf2) * 5120 + lane * 8;   // frag-linear
    bfc[nf2] = is_dp ? bfv[n0 + nf2 * 16 + lr] : 0.f;
  }
  f32x4 acc[4][4];
  #pragma unroll
  for (int mf = 0; mf < 4; ++mf)
    #pragma unroll
    for (int nf2 = 0; nf2 < 4; ++nf2)
      acc[mf][nf2] = (f32x4){0.f, 0.f, 0.f, 0.f};

  #pragma unroll 2
  for (int kk = 0; kk < 10; ++kk) {
    bf16x8 av[4], bv[4];
    #pragma unroll
    for (int mf = 0; mf < 4; ++mf) {
      int off = (lin[mf] + (kk << 6)) ^ xm[mf];
      av[mf] = __builtin_bit_cast(bf16x8, *(const short8*)((const char*)As + off));
    }
    #pragma unroll
    for (int nf2 = 0; nf2 < 4; ++nf2)
      bv[nf2] = __builtin_bit_cast(bf16x8, *(const short8*)(bptr[nf2] + kk * 512));
    #pragma unroll
    for (int mf = 0; mf < 4; ++mf)
      #pragma unroll
      for (int nf2 = 0; nf2 < 4; ++nf2)
        acc[mf][nf2] = __builtin_amdgcn_mfma_f32_16x16x32_bf16(av[mf], bv[nf2], acc[mf][nf2], 0, 0, 0);
  }
  #pragma unroll
  for (int mf = 0; mf < 4; ++mf)
    #pragma unroll
    for (int nf2 = 0; nf2 < 4; ++nf2)
      #pragma unroll
      for (int rr = 0; rr < 4; ++rr) {
        int rowl = mf * 16 + g * 4 + rr;
        int grow = row0 + rowl;
        if (grow < nrows) {
          int col = n0 + nf2 * 16 + lr;
          out[(size_t)grow * NINNER + col] = acc[mf][nf2][rr] + bfc[nf2];
        }
      }
}

// ---------------- Kernel 2: fused joint + log-softmax slices ----------------
// 512 threads (8 waves), 64 rows x V=1024; wave w owns cols [w*128,(w+1)*128)
// as 2 subchunks of 64; mf=4 -> each B-frag feeds 4 MFMA. B reads are
// frag-linear coalesced. LDS 64 KB -> 2 blocks/CU, 16 waves/CU nominal.
// Fixed-shift softmax: plain sum-of-exp.
#define JROWS 64
__global__ __launch_bounds__(512) void joint_kernel(
    const float* __restrict__ ep, const float* __restrict__ dp,
    const short* __restrict__ WpB, const float* __restrict__ bp,
    const int* __restrict__ tgt,
    float* __restrict__ lpb_d, float* __restrict__ lpe_d) {
  extern __shared__ char hbuf[];  // 64 * 512 * 2 = 65536 B
  __shared__ int ep_off[JROWS], dp_off[JROWS], bld_off[JROWS], eld_off[JROWS], tgt_s[JROWS];
  __shared__ float l0_s[JROWS], lt_s[JROWS];
  __shared__ float ws_s[8][JROWS];

  const int tid = threadIdx.x;
  const int row0 = blockIdx.x * JROWS;

  if (tid < JROWS) {
    int gr = row0 + tid;
    if (gr < NROWS) {
      int b = gr / (T_DIM * UP1);
      int rem = gr - b * (T_DIM * UP1);
      int t = rem / UP1;
      int u = rem - t * UP1;
      ep_off[tid] = (b * T_DIM + t) * NINNER;
      dp_off[tid] = (b * UP1 + u) * NINNER;
      bld_off[tid] = (b * NDIAG_B + (t + u)) * UP1 + u;          // diag layout
      eld_off[tid] = (u < U_DIM) ? ((b * NDIAG_E + (t + u)) * U_DIM + u) : -1;
      tgt_s[tid] = (u < U_DIM) ? tgt[b * U_DIM + u] : 0;
    } else {
      ep_off[tid] = 0; dp_off[tid] = 0; bld_off[tid] = -1; eld_off[tid] = -1; tgt_s[tid] = 0;
    }
    l0_s[tid] = 0.f; lt_s[tid] = 0.f;
  }
  __syncthreads();

  // Phase A: h into LDS (bf16, swizzled)
  #pragma unroll 2
  for (int it = 0; it < 8; ++it) {
    int chunk = it * 512 + tid;    // 4096 chunks of 8
    int m = chunk >> 6, c = chunk & 63;
    short8 hv;
    #pragma unroll
    for (int j = 0; j < 8; ++j) hv[j] = 0;
    if (bld_off[m] >= 0) {
      const float* pe = ep + ep_off[m] + c * 8;
      const float* pd = dp + dp_off[m] + c * 8;
      float4 e0 = *(const float4*)pe;
      float4 e1 = *(const float4*)(pe + 4);
      float4 d0 = *(const float4*)pd;
      float4 d1 = *(const float4*)(pd + 4);
      hv[0] = (short)f2bf(tanh_fast(e0.x + d0.x));
      hv[1] = (short)f2bf(tanh_fast(e0.y + d0.y));
      hv[2] = (short)f2bf(tanh_fast(e0.z + d0.z));
      hv[3] = (short)f2bf(tanh_fast(e0.w + d0.w));
      hv[4] = (short)f2bf(tanh_fast(e1.x + d1.x));
      hv[5] = (short)f2bf(tanh_fast(e1.y + d1.y));
      hv[6] = (short)f2bf(tanh_fast(e1.z + d1.z));
      hv[7] = (short)f2bf(tanh_fast(e1.w + d1.w));
    }
    int off = ((m << 10) + (c << 4)) ^ ((m & 7) << 4);
    *(short8*)(hbuf + off) = hv;
  }
  __syncthreads();

  const int lane = tid & 63, wid = tid >> 6;
  const int lr = lane & 15, g = lane >> 4;

  int lin[4], xm[4];
  #pragma unroll
  for (int mf = 0; mf < 4; ++mf) {
    int row = mf * 16 + lr;
    lin[mf] = (row << 10) + (g << 4);
    xm[mf] = (row & 7) << 4;
  }
  int tv[4][4];
  #pragma unroll
  for (int mf = 0; mf < 4; ++mf)
    #pragma unroll
    for (int rr = 0; rr < 4; ++rr)
      tv[mf][rr] = tgt_s[mf * 16 + g * 4 + rr];

  float rsum[4][4];
  #pragma unroll
  for (int mf = 0; mf < 4; ++mf)
    #pragma unroll
    for (int rr = 0; rr < 4; ++rr) rsum[mf][rr] = 0.f;

  #pragma unroll
  for (int sc = 0; sc < 2; ++sc) {
    const int n0 = wid * 128 + sc * 64;
    const short* bptr[4];
    float bpv[4];
    #pragma unroll
    for (int nf = 0; nf < 4; ++nf) {
      bptr[nf] = WpB + (n0 / 16 + nf) * 8192 + lane * 8;   // frag-linear
      bpv[nf] = bp[n0 + nf * 16 + lr];
    }
    f32x4 acc[4][4];
    #pragma unroll
    for (int mf = 0; mf < 4; ++mf)
      #pragma unroll
      for (int nf = 0; nf < 4; ++nf)
        acc[mf][nf] = (f32x4){0.f, 0.f, 0.f, 0.f};

    #pragma unroll 2
    for (int kk = 0; kk < 16; ++kk) {
      bf16x8 av[4], bv[4];
      #pragma unroll
      for (int mf = 0; mf < 4; ++mf) {
        int off = (lin[mf] + (kk << 6)) ^ xm[mf];
        av[mf] = __builtin_bit_cast(bf16x8, *(const short8*)(hbuf + off));
      }
      #pragma unroll
      for (int nf = 0; nf < 4; ++nf)
        bv[nf] = __builtin_bit_cast(bf16x8, *(const short8*)(bptr[nf] + kk * 512));
      #pragma unroll
      for (int mf = 0; mf < 4; ++mf)
        #pragma unroll
        for (int nf = 0; nf < 4; ++nf)
          acc[mf][nf] = __builtin_amdgcn_mfma_f32_16x16x32_bf16(av[mf], bv[nf], acc[mf][nf], 0, 0, 0);
    }
    // fold: plain sum-of-exp (shift 0) over this 64-col subchunk
    #pragma unroll
    for (int mf = 0; mf < 4; ++mf)
      #pragma unroll
      for (int rr = 0; rr < 4; ++rr) {
        float x0 = acc[mf][0][rr] + bpv[0];
        float x1 = acc[mf][1][rr] + bpv[1];
        float x2 = acc[mf][2][rr] + bpv[2];
        float x3 = acc[mf][3][rr] + bpv[3];
        int rowl = mf * 16 + g * 4 + rr;
        if (wid == 0 && sc == 0 && lr == 0) l0_s[rowl] = x0;  // v = 0
        int dtv = tv[mf][rr] - n0;
        if (dtv >= 0 && dtv < 64 && (dtv & 15) == lr) {
          int nfi = dtv >> 4;
          lt_s[rowl] = (nfi == 0) ? x0 : (nfi == 1) ? x1 : (nfi == 2) ? x2 : x3;
        }
        rsum[mf][rr] += fexp(x0) + fexp(x1) + fexp(x2) + fexp(x3);
      }
  }
  // add-butterfly across the 16 lanes of each group
  #pragma unroll
  for (int mf = 0; mf < 4; ++mf)
    #pragma unroll
    for (int rr = 0; rr < 4; ++rr) {
      float s_ = rsum[mf][rr];
      #pragma unroll
      for (int o = 1; o < 16; o <<= 1) s_ += __shfl_xor(s_, o);
      if (lr == 0) ws_s[wid][mf * 16 + g * 4 + rr] = s_;
    }
  __syncthreads();
  if (tid < JROWS) {
    int bo = bld_off[tid];
    if (bo >= 0) {
      float S = 0.f;
      #pragma unroll
      for (int w = 0; w < 8; ++w) S += ws_s[w][tid];
      float lse = flog(S);
      lpb_d[bo] = l0_s[tid] - lse;
      int eo = eld_off[tid];
      if (eo >= 0) lpe_d[eo] = lt_s[tid] - lse;
    }
  }
}

// ---------------- Kernel 3: alpha wavefront DP + loss ----------------
// 1 block x 256 threads; wave w owns batch b=w, fully independent (no
// __syncthreads anywhere). 380 serial diagonal steps; the r5 version was
// ~1024 cy/step — exposed HBM/L3 latency on the per-step lp loads (VGPR=32:
// compiler didn't keep the depth-4 ring in flight). Fix: chunk 16 diagonals,
// double-buffer in LDS. Per chunk: issue next chunk's global loads into regs
// (no wait) -> 16 serial steps read current LDS buffer (ds_read overlaps the
// ds_bpermute shuffles) -> vmcnt-wait + ds_write next chunk (loads have had
// ~16 steps of cover). Math identical to validated r5.
#define ACHUNK 16
#define NCHUNK 24   /* 24*16 = 384 >= 380 steps; extra steps compute NEG */
#define LB_FLOATS (ACHUNK * UP1)    /* 1296 */
#define LE_FLOATS (ACHUNK * U_DIM)  /* 1280 */
#define LE_BASE   (2 * B_DIM * LB_FLOATS) /* 10368 */
__global__ __launch_bounds__(256) void alpha_kernel(
    const float* __restrict__ lpb_d, const float* __restrict__ lpe_d,
    const int* __restrict__ ilen, const int* __restrict__ ulen_,
    float* __restrict__ out) {
  extern __shared__ float sbuf[];  // 82432 B: Lb[2][4][1296] + Le[2][4][1280]
  __shared__ float lls[B_DIM];
  const int tid = threadIdx.x;
  const int b = tid >> 6;
  const int lane = tid & 63;
  const float NEG = -1e30f;
  const int tl = ilen[b], ul = ulen_[b];

  const int u0 = lane;           // slot 0: u = 0..63
  const int u1 = 64 + lane;      // slot 1: u = 64..80 (lane < 17)
  const bool act1 = (u1 <= 80);

  const float* pb = lpb_d + (size_t)b * (NDIAG_B * UP1);
  const float4* pb4 = (const float4*)pb;
  const float4* pe4 = (const float4*)(lpe_d + (size_t)b * (NDIAG_E * U_DIM));
  const int PB4MAX = (NDIAG_B * UP1) / 4 - 1;   // 7694
  const int PE4MAX = (NDIAG_E * U_DIM) / 4 - 1; // 7579

  float4 rb[6], re[5];

  // ---- staging helpers (per-wave; no cross-wave sync needed) ----
  // chunk c covers diag indices dd = 16c .. 16c+15
  #define LOAD_CHUNK(c)                                                     \
    {                                                                       \
      int gb_ = (c) * (LB_FLOATS / 4), ge_ = (c) * (LE_FLOATS / 4);         \
      _Pragma("unroll")                                                     \
      for (int i = 0; i < 6; ++i) {                                         \
        int v = i * 64 + lane;                                              \
        if (v < LB_FLOATS / 4) {                                            \
          int gv = gb_ + v; if (gv > PB4MAX) gv = PB4MAX;                   \
          rb[i] = pb4[gv];                                                  \
        }                                                                   \
      }                                                                     \
      _Pragma("unroll")                                                     \
      for (int i = 0; i < 5; ++i) {                                         \
        int v = i * 64 + lane;                                              \
        int gv = ge_ + v; if (gv > PE4MAX) gv = PE4MAX;                     \
        re[i] = pe4[gv];                                                    \
      }                                                                     \
    }
  #define WRITE_CHUNK(c)                                                    \
    {                                                                       \
      int h_ = (c) & 1;                                                     \
      float* Lb_ = sbuf + (h_ * B_DIM + b) * LB_FLOATS;                     \
      float* Le_ = sbuf + LE_BASE + (h_ * B_DIM + b) * LE_FLOATS;           \
      _Pragma("unroll")                                                     \
      for (int i = 0; i < 6; ++i) {                                         \
        int v = i * 64 + lane;                                              \
        if (v < LB_FLOATS / 4) *(float4*)(Lb_ + v * 4) = rb[i];             \
      }                                                                     \
      _Pragma("unroll")                                                     \
      for (int i = 0; i < 5; ++i) {                                         \
        int v = i * 64 + lane;                                              \
        *(float4*)(Le_ + v * 4) = re[i];                                    \
      }                                                                     \
    }

  LOAD_CHUNK(0);
  WRITE_CHUNK(0);

  float pa0 = (u0 == 0) ? 0.f : NEG;  // alpha on diag 0
  float pa1 = NEG;
  float fin = NEG;

  for (int c = 0; c < NCHUNK; ++c) {
    if (c + 1 < NCHUNK) LOAD_CHUNK(c + 1);   // issue early, no wait
    const int h = c & 1;
    const float* Lb = sbuf + (h * B_DIM + b) * LB_FLOATS;
    const float* Le = sbuf + LE_BASE + (h * B_DIM + b) * LE_FLOATS;
    #pragma unroll
    for (int j = 0; j < ACHUNK; ++j) {
      const int d = c * ACHUNK + j + 1;
      // operands for step d live at diag dd = d-1 = local row j
      float bl0 = Lb[j * UP1 + u0];
      float em0 = (u0 >= 1) ? Le[j * U_DIM + u0 - 1] : NEG;
      float bl1 = act1 ? Lb[j * UP1 + u1] : NEG;
      float em1 = act1 ? Le[j * U_DIM + u1 - 1] : NEG;
      float n0t = __shfl(pa0, (lane + 63) & 63);
      float n1t = __shfl(pa1, (lane + 63) & 63);
      float n0_63 = __shfl(pa0, 63);
      // slot 0
      float v0;
      {
        int t = d - u0;
        bool cell = (t >= 0 && t <= T_DIM - 1);
        float a = (cell && t >= 1) ? pa0 + bl0 : NEG;
        float e = (cell && u0 >= 1) ? n0t + em0 : NEG;
        float mx = fmaxf(a, e), mn = fminf(a, e);
        v0 = cell ? mx + flog(1.0f + fexp(mn - mx)) : NEG;
        if (u0 == ul && t == tl - 1) fin = v0;
      }
      // slot 1
      {
        int t = d - u1;
        float nem = (lane == 0) ? n0_63 : n1t;
        bool cell = act1 && (t >= 0 && t <= T_DIM - 1);
        float a = (cell && t >= 1) ? pa1 + bl1 : NEG;
        float e = cell ? nem + em1 : NEG;   // u1 >= 64 >= 1 always
        float mx = fmaxf(a, e), mn = fminf(a, e);
        float v1 = cell ? mx + flog(1.0f + fexp(mn - mx)) : NEG;
        if (act1 && u1 == ul && t == tl - 1) fin = v1;
        pa1 = v1;
      }
      pa0 = v0;
    }
    if (c + 1 < NCHUNK) WRITE_CHUNK(c + 1);  // vmcnt wait lands here, covered
  }

  // reduce fin across the wave (only one lane set it)
  #pragma unroll
  for (int o = 32; o; o >>= 1) fin = fmaxf(fin, __shfl_xor(fin, o));
  if (lane == 0) {
    float last = pb[(size_t)(tl - 1 + ul) * UP1 + ul];
    lls[b] = fin + last;
  }
  __syncthreads();
  if (tid == 0)
    out[0] = -(lls[0] + lls[1] + lls[2] + lls[3]) * (1.0f / (float)B_DIM);
}

// ---------------- launcher ----------------
extern "C" void kernel_launch(void* const* d_in, const int* in_sizes, int n_in,
                              void* d_out, int out_size, void* d_ws, size_t ws_size,
                              hipStream_t stream) {
  const float* enc = (const float*)d_in[0];
  const float* dec = (const float*)d_in[1];
  const float* Wf  = (const float*)d_in[2];
  const float* bfv = (const float*)d_in[3];
  const float* Wp  = (const float*)d_in[4];
  const float* bp  = (const float*)d_in[5];
  const int* targets = (const int*)d_in[6];
  const int* ilen    = (const int*)d_in[7];
  const int* ulen    = (const int*)d_in[8];
  float* out = (float*)d_out;
  char* ws = (char*)d_ws;

  short* WfB   = (short*)(ws + 0);          //   655360 B (packed)
  short* WpB   = (short*)(ws + 655360);     //  1048576 B (packed)
  float* ep    = (float*)(ws + 1703936);    //  2457600 B
  float* dp    = (float*)(ws + 4161536);    //   663552 B
  float* lpb_d = (float*)(ws + 4825088);    //   492480 B (4*380*81)
  float* lpe_d = (float*)(ws + 5317568);    //   485120 B (4*379*80) -> 5802688 B

  cvt_kernel<<<832, 256, 0, stream>>>(Wf, Wp, WfB, WpB);
  proj_kernel<<<50, 256, 0, stream>>>(enc, dec, WfB, bfv, ep, dp);
  joint_kernel<<<(NROWS + JROWS - 1) / JROWS, 512, 65536, stream>>>(ep, dp, WpB, bp, targets, lpb_d, lpe_d);
  alpha_kernel<<<1, 256, 82432, stream>>>(lpb_d, lpe_d, ilen, ulen, out);
}